// Round 10
// baseline (10114.229 us; speedup 1.0000x reference)
//
#include <hip/hip_runtime.h>
#include <hip/hip_bf16.h>
#include <math.h>

// Problem dims
#define B_  48
#define T_  200
#define C_  53
#define H_  64
#define C2_ 2809
#define E1_ 140
#define E2_ 1404
#define TS  60          // padded LDS row stride (floats)

typedef long long i64;

struct __align__(16) F4 { float v[4]; };
struct __align__(8)  F2 { float v[2]; };

__device__ __forceinline__ float wredsum(float v){
  #pragma unroll
  for (int o = 32; o > 0; o >>= 1) v += __shfl_xor(v, o);
  return v;
}
__device__ __forceinline__ float sigm(float x){ return 1.f/(1.f + __expf(-x)); }
__device__ __forceinline__ float tanhx(float x){
  float a = fabsf(x);
  float e = __expf(-2.f*a);
  float t = (1.f - e)/(1.f + e);
  return copysignf(t, x);
}

// 2-row x 4-col eigen squaring tile: Y = (X@X)*inv, fused ssq/trace stats.
// Reads a-rows r0,r0+1 (<=53, row 53 must be zero in X); writes unguarded
// (zero rows propagate, cleaning stale pads).
__device__ __forceinline__ void eig_mm(const float* __restrict__ X, float* __restrict__ Y,
                                       int r0, int c0, float inv,
                                       float& essq, float& etrc){
  float ea0[4] = {0.f,0.f,0.f,0.f};
  float ea1[4] = {0.f,0.f,0.f,0.f};
  for (int kq = 0; kq < 13; kq++){
    int k4 = kq*4;
    F4 a0 = *(const F4*)&X[(r0+0)*TS + k4];
    F4 a1 = *(const F4*)&X[(r0+1)*TS + k4];
    F4 b0 = *(const F4*)&X[(k4+0)*TS + c0];
    F4 b1 = *(const F4*)&X[(k4+1)*TS + c0];
    F4 b2 = *(const F4*)&X[(k4+2)*TS + c0];
    F4 b3 = *(const F4*)&X[(k4+3)*TS + c0];
    #pragma unroll
    for (int ci = 0; ci < 4; ci++){
      ea0[ci] += a0.v[0]*b0.v[ci] + a0.v[1]*b1.v[ci] + a0.v[2]*b2.v[ci] + a0.v[3]*b3.v[ci];
      ea1[ci] += a1.v[0]*b0.v[ci] + a1.v[1]*b1.v[ci] + a1.v[2]*b2.v[ci] + a1.v[3]*b3.v[ci];
    }
  }
  {
    float a0 = X[(r0+0)*TS + 52], a1 = X[(r0+1)*TS + 52];
    F4 bb = *(const F4*)&X[52*TS + c0];
    #pragma unroll
    for (int ci = 0; ci < 4; ci++){ ea0[ci] += a0*bb.v[ci]; ea1[ci] += a1*bb.v[ci]; }
  }
  F4 o0, o1;
  #pragma unroll
  for (int ci = 0; ci < 4; ci++){
    o0.v[ci] = ea0[ci]*inv;
    o1.v[ci] = ea1[ci]*inv;
    essq += o0.v[ci]*o0.v[ci] + o1.v[ci]*o1.v[ci];
  }
  if (r0   >= c0 && r0   < c0+4) etrc += o0.v[r0-c0];
  if (r0+1 >= c0 && r0+1 < c0+4) etrc += o1.v[r0+1-c0];
  *(F4*)&Y[(r0+0)*TS + c0] = o0;
  *(F4*)&Y[(r0+1)*TS + c0] = o1;
}

// 3-row x 4-col first squaring tile (rows r0..r0+2, r0<=51; verified spill-free in r7)
__device__ __forceinline__ void eig_mm3(const float* __restrict__ X, float* __restrict__ Y,
                                        int r0, int c0, float inv,
                                        float& essq, float& etrc){
  float ea0[4] = {0.f,0.f,0.f,0.f};
  float ea1[4] = {0.f,0.f,0.f,0.f};
  float ea2[4] = {0.f,0.f,0.f,0.f};
  for (int kq = 0; kq < 13; kq++){
    int k4 = kq*4;
    F4 a0 = *(const F4*)&X[(r0+0)*TS + k4];
    F4 a1 = *(const F4*)&X[(r0+1)*TS + k4];
    F4 a2 = *(const F4*)&X[(r0+2)*TS + k4];
    F4 b0 = *(const F4*)&X[(k4+0)*TS + c0];
    F4 b1 = *(const F4*)&X[(k4+1)*TS + c0];
    F4 b2 = *(const F4*)&X[(k4+2)*TS + c0];
    F4 b3 = *(const F4*)&X[(k4+3)*TS + c0];
    #pragma unroll
    for (int ci = 0; ci < 4; ci++){
      ea0[ci] += a0.v[0]*b0.v[ci] + a0.v[1]*b1.v[ci] + a0.v[2]*b2.v[ci] + a0.v[3]*b3.v[ci];
      ea1[ci] += a1.v[0]*b0.v[ci] + a1.v[1]*b1.v[ci] + a1.v[2]*b2.v[ci] + a1.v[3]*b3.v[ci];
      ea2[ci] += a2.v[0]*b0.v[ci] + a2.v[1]*b1.v[ci] + a2.v[2]*b2.v[ci] + a2.v[3]*b3.v[ci];
    }
  }
  {
    float a0 = X[(r0+0)*TS + 52], a1 = X[(r0+1)*TS + 52], a2 = X[(r0+2)*TS + 52];
    F4 bb = *(const F4*)&X[52*TS + c0];
    #pragma unroll
    for (int ci = 0; ci < 4; ci++){
      ea0[ci] += a0*bb.v[ci]; ea1[ci] += a1*bb.v[ci]; ea2[ci] += a2*bb.v[ci];
    }
  }
  F4 o0, o1, o2;
  #pragma unroll
  for (int ci = 0; ci < 4; ci++){
    o0.v[ci] = ea0[ci]*inv;
    o1.v[ci] = ea1[ci]*inv;
    o2.v[ci] = ea2[ci]*inv;
    essq += o0.v[ci]*o0.v[ci] + o1.v[ci]*o1.v[ci] + o2.v[ci]*o2.v[ci];
  }
  if (r0   >= c0 && r0   < c0+4) etrc += o0.v[r0-c0];
  if (r0+1 >= c0 && r0+1 < c0+4) etrc += o1.v[r0+1-c0];
  if (r0+2 >= c0 && r0+2 < c0+4) etrc += o2.v[r0+2-c0];
  *(F4*)&Y[(r0+0)*TS + c0] = o0;
  *(F4*)&Y[(r0+1)*TS + c0] = o1;
  *(F4*)&Y[(r0+2)*TS + c0] = o2;
}

// ---------------- ws layout (float offsets) ----------------
#define OFF_SIGMA 0
#define OFF_WHHT  200
#define OFF_WZV   12488
#define OFF_WUV   20680
#define OFF_P     20812
#define OFF_R0    21004
#define OFF_MM    21196
#define OFF_M2    25292
#define OFF_M4    29388
#define OFF_M5    33484
#define OFF_AMEAN 37580
#define OFF_E     172412
#define OFF_CA    1516412
#define OFF_CB    1516552
#define OFF_APRE  1516692
#define OFF_A     1526292
#define OFF_G2T   1535892

// ---------------- prep1: transposes + G=Wq^T Wk + u-vectors + p/r0 ----------------
__global__ void k_prep1(const float* __restrict__ w_hh, const float* __restrict__ wq,
                        const float* __restrict__ wk, const float* __restrict__ wv,
                        const float* __restrict__ w_ih, const float* __restrict__ emb_w,
                        const float* __restrict__ emb_b, const float* __restrict__ b_ih,
                        const float* __restrict__ bq, const float* __restrict__ bk,
                        const float* __restrict__ w_g2,
                        float* whhT, float* wzv, float* wuv, float* g2t,
                        float* p, float* r0){
  int idx0 = blockIdx.x*blockDim.x + threadIdx.x;
  int stride = gridDim.x*blockDim.x;
  for (int i = idx0; i < 64*192; i += stride){
    int kk = i/192, g = i%192;
    whhT[i] = w_hh[g*64 + kk];
  }
  // wzv[h][0..63] = G[h][a] = sum_m wq[m][h]*wk[m][a]; wzv[h][64..127] = wv[a][h]
  for (int i = idx0; i < 8192; i += stride){
    int h = i >> 7, a = i & 127;
    if (a < 64){
      float g = 0.f;
      for (int m = 0; m < 64; m++) g += wq[m*64 + h]*wk[m*64 + a];
      wzv[i] = g;
    } else {
      wzv[i] = wv[(a-64)*64 + h];
    }
  }
  for (int i = idx0; i < 129; i += stride){
    if (i < 64){
      float s = 0.f;
      for (int m = 0; m < 64; m++) s += wq[m*64 + i]*bk[m];
      wuv[i] = s;
    } else if (i < 128){
      int h = i - 64;
      float s = 0.f;
      for (int m = 0; m < 64; m++) s += wk[m*64 + h]*bq[m];
      wuv[i] = s;
    } else {
      float s = 0.f;
      for (int m = 0; m < 64; m++) s += bq[m]*bk[m];
      wuv[128] = s;
    }
  }
  for (int i = idx0; i < 140*1404; i += stride){ int k = i/1404, n = i%1404; g2t[i] = w_g2[n*140+k]; }
  for (int i = idx0; i < 192; i += stride){
    float s1 = 0.f, s2 = 0.f;
    for (int e = 0; e < 32; e++){ float w = w_ih[i*32+e]; s1 += w*emb_w[e]; s2 += w*emb_b[e]; }
    p[i] = s1; r0[i] = s2 + b_ih[i];
  }
}

// ---------------- prep2: M powers + sigma[t] (serial power iteration) ----------------
__global__ void k_prep2(const float* __restrict__ wv, const float* __restrict__ u0,
                        float* Wm, float* Wm2, float* Wm4, float* Wm5, float* sigma){
  int r = threadIdx.x; // 64 threads, one wave
  for (int c = 0; c < 64; c++){
    float s = 0.f;
    for (int k = 0; k < 64; k++) s += wv[r*64+k]*wv[c*64+k];
    Wm[r*64+c] = s;
  }
  __syncthreads();
  for (int c = 0; c < 64; c++){
    float s = 0.f;
    for (int k = 0; k < 64; k++) s += Wm[r*64+k]*Wm[k*64+c];
    Wm2[r*64+c] = s;
  }
  __syncthreads();
  for (int c = 0; c < 64; c++){
    float s = 0.f;
    for (int k = 0; k < 64; k++) s += Wm2[r*64+k]*Wm2[k*64+c];
    Wm4[r*64+c] = s;
  }
  __syncthreads();
  for (int c = 0; c < 64; c++){
    float s = 0.f;
    for (int k = 0; k < 64; k++) s += Wm4[r*64+k]*Wm[k*64+c];
    Wm5[r*64+c] = s;
  }
  __syncthreads();
  __shared__ float su[64];
  su[r] = u0[r];
  __syncthreads();
  for (int t = 0; t < T_; t++){
    float z = 0.f, w = 0.f;
    for (int k = 0; k < 64; k++){ float uk = su[k]; z += Wm4[r*64+k]*uk; w += Wm5[r*64+k]*uk; }
    float nw = wredsum(w*w);
    float zw = wredsum(z*w);
    float sg = sqrtf(nw / fmaxf(zw, 1e-35f));
    if (r == 0) sigma[t] = sg;
    float wn = w * (1.f/sqrtf(fmaxf(nw, 1e-35f)));
    __syncthreads();
    su[r] = wn;
    __syncthreads();
  }
}

// ---------------- the scan: one WG per batch, all 200 steps on-chip ----------------
// r9 base (7.12ms verified) + (1) h_raw merged into phase D (r7-verified layout,
// raw->Rh, scaled in F), (2) eigen exit floor J>=3 (convergence-gated).
__global__ __launch_bounds__(512, 1) void k_scan(
    const float* __restrict__ x, const float* __restrict__ b_hh,
    const float* __restrict__ bv,
    const float* __restrict__ whhT, const float* __restrict__ wzv,
    const float* __restrict__ wuv,
    const float* __restrict__ wp, const float* __restrict__ wr0,
    const float* __restrict__ sigma, float* __restrict__ outAL){
  __shared__ __align__(16) float L[19056];
  float* Rh  = L;            // [64][60] h (persistent); raw h_raw during E
  float* R4  = L + 3840;     // [64][60] hg -> eigen pong
  float* R3  = L + 7680;     // [64][60] ZT -> eigen ping
  float* R2  = L + 11520;    // [53][64] val (dead after D)
  float* R1  = L + 14912;    // [56][60] S (preserved all step)
  float* Lp  = L + 18272;    // 192
  float* Lr0 = L + 18464;    // 192
  float* Lbh = L + 18656;    // 192
  float* Lbv = L + 18848;    // 64
  float* Lrq = L + 18912;    // 56
  float* Lrk = L + 18968;    // 56
  float* Lsc = L + 19024;    // 32: [2j]=ssq_j, [2j+1]=tr_j
  int tid = threadIdx.x;
  int b = blockIdx.x;

  for (int i = tid; i < 192; i += 512){ Lp[i] = wp[i]; Lr0[i] = wr0[i]; Lbh[i] = b_hh[i]; }
  for (int i = tid; i < 64; i += 512) Lbv[i] = bv[i];
  for (int i = tid; i < 18272; i += 512) L[i] = 0.f;  // zero Rh..R1 (h0=0, pads)
  __syncthreads();

  int ct4 = tid >> 4, jt4 = tid & 15;   // 224-thread tilings (GH)
  int c0g = ct4*4, j0g = jt4*4;
  int it14 = tid/14, jt14 = tid%14;     // 196-thread scores tiling
  int i0s = it14*4, j0s = jt14*4;
  int ctq = tid >> 5, gtq = tid & 31;   // 448-thread QKV tiling
  int c0q = ctq*4, g0q = gtq*4;
  int erg = tid/14, ecg = tid%14;       // 378-thread eigen tiling (2x4)
  int er0 = erg*2, ec0 = ecg*4;

  const float c0v = wuv[128];

  for (int t = 0; t < T_; t++){
    // ---- A: GH + gates fused: gh = h @ w_hh^T (+b_hh); hg -> R4 (224 thr) ----
    if (tid < 32) Lsc[tid] = 0.f;
    if (tid < 224){
      float gacc[3][4][4];
      #pragma unroll
      for (int g = 0; g < 3; g++)
        #pragma unroll
        for (int ji = 0; ji < 4; ji++){
          float bb = Lbh[g*64 + j0g + ji];
          #pragma unroll
          for (int ci = 0; ci < 4; ci++) gacc[g][ji][ci] = bb;
        }
      for (int kk = 0; kk < 64; kk++){
        F4 hv = *(F4*)&Rh[kk*TS + c0g];
        F4 w0 = *(const F4*)&whhT[kk*192 + j0g];
        F4 w1 = *(const F4*)&whhT[kk*192 + 64 + j0g];
        F4 w2 = *(const F4*)&whhT[kk*192 + 128 + j0g];
        #pragma unroll
        for (int ji = 0; ji < 4; ji++)
          #pragma unroll
          for (int ci = 0; ci < 4; ci++){
            gacc[0][ji][ci] += hv.v[ci]*w0.v[ji];
            gacc[1][ji][ci] += hv.v[ci]*w1.v[ji];
            gacc[2][ji][ci] += hv.v[ci]*w2.v[ji];
          }
      }
      float xv[4];
      #pragma unroll
      for (int ci = 0; ci < 4; ci++){
        int c = c0g + ci;
        xv[ci] = (c < C_) ? x[(i64)(b*T_ + t)*C_ + c] : 0.f;
      }
      F4 p0 = *(F4*)&Lp[j0g], p1 = *(F4*)&Lp[64+j0g], p2 = *(F4*)&Lp[128+j0g];
      F4 q0 = *(F4*)&Lr0[j0g], q1 = *(F4*)&Lr0[64+j0g], q2 = *(F4*)&Lr0[128+j0g];
      #pragma unroll
      for (int ji = 0; ji < 4; ji++){
        F4 hold = *(F4*)&Rh[(j0g+ji)*TS + c0g];
        F4 o;
        #pragma unroll
        for (int ci = 0; ci < 4; ci++){
          float rr = sigm(xv[ci]*p0.v[ji] + q0.v[ji] + gacc[0][ji][ci]);
          float zz = sigm(xv[ci]*p1.v[ji] + q1.v[ji] + gacc[1][ji][ci]);
          float nn = tanhx(xv[ci]*p2.v[ji] + q2.v[ji] + rr*gacc[2][ji][ci]);
          float hg = (1.f - zz)*nn + zz*hold.v[ci];
          o.v[ci] = (c0g + ci < C_) ? hg : 0.f;
        }
        *(F4*)&R4[(j0g+ji)*TS + c0g] = o;
      }
    }
    __syncthreads();
    // ---- B: projections: ZT = (hg G)^T -> R3, val -> R2 (448); rank-1 vecs ----
    if (tid < 448){
      float acc[4][4];
      #pragma unroll
      for (int gi = 0; gi < 4; gi++)
        #pragma unroll
        for (int ci = 0; ci < 4; ci++) acc[gi][ci] = 0.f;
      for (int kk = 0; kk < 64; kk++){
        F4 a = *(F4*)&R4[kk*TS + c0q];
        F4 w = *(const F4*)&wzv[kk*128 + g0q];
        #pragma unroll
        for (int gi = 0; gi < 4; gi++)
          #pragma unroll
          for (int ci = 0; ci < 4; ci++) acc[gi][ci] += a.v[ci]*w.v[gi];
      }
      if (g0q < 64){
        #pragma unroll
        for (int gi = 0; gi < 4; gi++){
          F4 o;
          #pragma unroll
          for (int ci = 0; ci < 4; ci++) o.v[ci] = acc[gi][ci];
          *(F4*)&R3[(g0q+gi)*TS + c0q] = o;
        }
      } else {
        float invs = 1.f/sigma[t];
        int a0i = g0q - 64;
        #pragma unroll
        for (int ci = 0; ci < 4; ci++){
          int c = c0q + ci;
          if (c < C_){
            F4 o;
            #pragma unroll
            for (int gi = 0; gi < 4; gi++) o.v[gi] = acc[gi][ci]*invs + Lbv[a0i+gi];
            *(F4*)&R2[c*64 + a0i] = o;
          }
        }
      }
    } else if (tid < 504){
      int u = tid - 448;
      float rq = 0.f, rk = 0.f;
      if (u < C_){
        for (int h = 0; h < 64; h++){
          float hv = R4[h*TS + u];
          rq += hv*wuv[h];
          rk += hv*wuv[64+h];
        }
      }
      if (u < 56){ Lrq[u] = rq; Lrk[u] = rk; }
    }
    __syncthreads();
    // ---- C: scores S = ZT^T.hgT + rank1 -> R1 (196 thr, 4x4); stats ----
    {
      float sacc[4][4];
      float ssq = 0.f, trc = 0.f;
      if (tid < 196){
        #pragma unroll
        for (int ii = 0; ii < 4; ii++)
          #pragma unroll
          for (int jj = 0; jj < 4; jj++){
            int i = i0s + ii, j = j0s + jj;
            sacc[ii][jj] = (i < C_ && j < C_) ? (Lrq[i] + Lrk[j] + c0v) : 0.f;
          }
        for (int aq = 0; aq < 16; aq++){
          int a4 = aq*4;
          F4 qa0 = *(F4*)&R3[(a4+0)*TS + i0s];
          F4 qa1 = *(F4*)&R3[(a4+1)*TS + i0s];
          F4 qa2 = *(F4*)&R3[(a4+2)*TS + i0s];
          F4 qa3 = *(F4*)&R3[(a4+3)*TS + i0s];
          F4 kb0 = *(F4*)&R4[(a4+0)*TS + j0s];
          F4 kb1 = *(F4*)&R4[(a4+1)*TS + j0s];
          F4 kb2 = *(F4*)&R4[(a4+2)*TS + j0s];
          F4 kb3 = *(F4*)&R4[(a4+3)*TS + j0s];
          #pragma unroll
          for (int ii = 0; ii < 4; ii++)
            #pragma unroll
            for (int jj = 0; jj < 4; jj++)
              sacc[ii][jj] += qa0.v[ii]*kb0.v[jj] + qa1.v[ii]*kb1.v[jj]
                            + qa2.v[ii]*kb2.v[jj] + qa3.v[ii]*kb3.v[jj];
        }
        #pragma unroll
        for (int ii = 0; ii < 4; ii++){
          int i = i0s + ii;
          if (i < C_){
            F4 o;
            #pragma unroll
            for (int jj = 0; jj < 4; jj++){
              o.v[jj] = sacc[ii][jj];
              ssq += sacc[ii][jj]*sacc[ii][jj];
            }
            *(F4*)&R1[i*TS + j0s] = o;
            if (j0s <= i && i < j0s + 4) trc += sacc[ii][i - j0s];
          }
        }
      }
      ssq = wredsum(ssq); trc = wredsum(trc);
      if ((tid & 63) == 0){
        if (ssq != 0.f) atomicAdd(&Lsc[0], ssq);
        if (trc != 0.f) atomicAdd(&Lsc[1], trc);
      }
    }
    __syncthreads();
    // ---- D: X1 = S@S/ssq0 -> R3 (252 thr, 3x4) || h_raw RAW -> Rh (224 thr) ----
    {
      float essq = 0.f, etrc = 0.f;
      if (tid < 252){
        float inv0 = 1.f/fmaxf(Lsc[0], 1e-35f);
        int r0e = (tid/14)*3, c0e = (tid%14)*4;
        eig_mm3(R1, R3, r0e, c0e, inv0, essq, etrc);
      } else if (tid < 476){
        int u = tid - 252;
        int c0 = (u >> 4)*4, j0 = (u & 15)*4;
        float hr0[4] = {0.f,0.f,0.f,0.f};
        float hr1[4] = {0.f,0.f,0.f,0.f};
        float hr2[4] = {0.f,0.f,0.f,0.f};
        float hr3[4] = {0.f,0.f,0.f,0.f};
        for (int kq = 0; kq < 13; kq++){
          int k4 = kq*4;
          F4 a0 = *(F4*)&R1[(c0+0)*TS + k4];
          F4 a1 = *(F4*)&R1[(c0+1)*TS + k4];
          F4 a2 = *(F4*)&R1[(c0+2)*TS + k4];
          F4 a3 = *(F4*)&R1[(c0+3)*TS + k4];
          F4 b0 = *(F4*)&R2[(k4+0)*64 + j0];
          F4 b1 = *(F4*)&R2[(k4+1)*64 + j0];
          F4 b2 = *(F4*)&R2[(k4+2)*64 + j0];
          F4 b3 = *(F4*)&R2[(k4+3)*64 + j0];
          #pragma unroll
          for (int jj = 0; jj < 4; jj++){
            hr0[jj] += a0.v[0]*b0.v[jj] + a0.v[1]*b1.v[jj] + a0.v[2]*b2.v[jj] + a0.v[3]*b3.v[jj];
            hr1[jj] += a1.v[0]*b0.v[jj] + a1.v[1]*b1.v[jj] + a1.v[2]*b2.v[jj] + a1.v[3]*b3.v[jj];
            hr2[jj] += a2.v[0]*b0.v[jj] + a2.v[1]*b1.v[jj] + a2.v[2]*b2.v[jj] + a2.v[3]*b3.v[jj];
            hr3[jj] += a3.v[0]*b0.v[jj] + a3.v[1]*b1.v[jj] + a3.v[2]*b2.v[jj] + a3.v[3]*b3.v[jj];
          }
        }
        {
          const int k = 52;
          float a0 = R1[(c0+0)*TS + k], a1 = R1[(c0+1)*TS + k];
          float a2 = R1[(c0+2)*TS + k], a3 = R1[(c0+3)*TS + k];
          F4 bb = *(F4*)&R2[k*64 + j0];
          #pragma unroll
          for (int jj = 0; jj < 4; jj++){
            hr0[jj] += a0*bb.v[jj];
            hr1[jj] += a1*bb.v[jj];
            hr2[jj] += a2*bb.v[jj];
            hr3[jj] += a3*bb.v[jj];
          }
        }
        #pragma unroll
        for (int jj = 0; jj < 4; jj++){
          F4 o;
          o.v[0] = (c0 + 0 < C_) ? hr0[jj] : 0.f;
          o.v[1] = (c0 + 1 < C_) ? hr1[jj] : 0.f;
          o.v[2] = (c0 + 2 < C_) ? hr2[jj] : 0.f;
          o.v[3] = (c0 + 3 < C_) ? hr3[jj] : 0.f;
          *(F4*)&Rh[(j0+jj)*TS + c0] = o;   // RAW; scaled by invm in phase F
        }
      }
      essq = wredsum(essq); etrc = wredsum(etrc);
      if ((tid & 63) == 0){
        if (essq != 0.f) atomicAdd(&Lsc[2], essq);
        if (etrc != 0.f) atomicAdd(&Lsc[3], etrc);
      }
    }
    __syncthreads();
    // ---- E: eigen squaring chain, fused stats (exit floor J>=3, conv-gated) ----
    float Gacc = 0.f, prevest = 1e30f, est = 0.f;
    int cnt = 0;
    float pssq = fmaxf(Lsc[0], 1e-35f), ptr1 = Lsc[1];
    float* Xb = R3; float* Yb = R4;
    for (int j = 2; j <= 13; j++){
      float sj = fmaxf(Lsc[2*(j-1)], 1e-35f);
      float tj = Lsc[2*(j-1)+1];
      int J = j - 2;
      float t1n = ptr1/sqrtf(pssq);
      float t2n = tj;
      float disc = 2.f*t2n - t1n*t1n;
      float rq = (disc >= 0.f) ? 0.5f*(fabsf(t1n) + sqrtf(disc))
                               : sqrtf(fmaxf(0.5f*(t1n*t1n - t2n), 1e-30f));
      rq = fminf(fmaxf(rq, 0.02f), 1.5f);
      est = Gacc + ldexpf(0.5f*log2f(pssq) + log2f(rq), -J);
      if (fabsf(est - prevest) < 1e-4f) cnt++; else cnt = 0;
      prevest = est;
      Gacc += ldexpf(log2f(pssq), -(J+1));
      if ((J >= 3 && cnt >= 1) || j == 13) break;
      pssq = sj; ptr1 = tj;
      {
        float inv = 1.f/sj;
        float essq = 0.f, etrc = 0.f;
        if (tid < 378) eig_mm(Xb, Yb, er0, ec0, inv, essq, etrc);
        essq = wredsum(essq); etrc = wredsum(etrc);
        if ((tid & 63) == 0){
          if (essq != 0.f) atomicAdd(&Lsc[2*j], essq);
          if (etrc != 0.f) atomicAdd(&Lsc[2*j+1], etrc);
        }
      }
      { float* tp = Xb; Xb = Yb; Yb = tp; }
      __syncthreads();
    }
    float invm = exp2f(-est);
    // ---- F: h' = hraw*invm in Rh (224 thr) ; align = S*invm -> global (196) ----
    if (tid < 224){
      for (int idx = tid; idx < 960; idx += 224){
        F4 v = *(F4*)&Rh[idx*4];
        #pragma unroll
        for (int u = 0; u < 4; u++) v.v[u] *= invm;
        *(F4*)&Rh[idx*4] = v;
      }
    } else if (tid < 420){
      int u = tid - 224;
      int i0 = (u/14)*4, j0 = (u%14)*4;
      float* ALrow = outAL + (i64)(b*T_ + t)*C2_;
      #pragma unroll
      for (int ii = 0; ii < 4; ii++){
        int i = i0 + ii;
        if (i < C_){
          F4 s = *(F4*)&R1[i*TS + j0];
          #pragma unroll
          for (int jj = 0; jj < 4; jj++){
            int jc = j0 + jj;
            if (jc < C_) ALrow[i*C_ + jc] = s.v[jj]*invm;
          }
        }
      }
    }
    __syncthreads();
  }
}

// ---------------- amean: T-mean of (already scaled) align ----------------
__global__ void k_amean(const float* __restrict__ AL, float* __restrict__ amean){
  int b = blockIdx.x/11, ch = blockIdx.x%11;
  int c2 = ch*256 + threadIdx.x;
  if (c2 >= C2_) return;
  float acc = 0.f;
  for (int t = 0; t < T_; t++)
    acc += AL[(i64)(b*T_ + t)*C2_ + c2];
  amean[(i64)b*C2_ + c2] = acc*(1.f/(float)T_);
}

// ---------------- e = (align * mean) @ w_g1^T  (K-split x4, atomics, 256 thr) ------
__global__ __launch_bounds__(256) void k_gemm1(const float* __restrict__ AL,
                                               const float* __restrict__ amean,
                                               const float* __restrict__ w_g1,
                                               float* __restrict__ e){
  __shared__ __align__(16) float At[64][68];
  __shared__ __align__(16) float Bt[64][148];
  int mt = blockIdx.x >> 2, ks = blockIdx.x & 3;
  int tid = threadIdx.x;
  float acc[4][10];
  #pragma unroll
  for (int ri = 0; ri < 4; ri++)
    #pragma unroll
    for (int ci = 0; ci < 10; ci++) acc[ri][ci] = 0.f;
  int rg = tid/14, cg = tid%14;   // 224 compute threads: 16 row-groups x 14 col-groups
  int r0 = rg*4, cc0 = cg*10;
  for (int kb = 0; kb < 11; kb++){
    int k0 = (ks*11 + kb)*64;
    for (int idx = tid; idx < 4096; idx += 256){
      int r = idx >> 6, i = idx & 63;
      int kk = k0 + i;
      int row = mt*64 + r, bb = row/T_;
      float v = 0.f;
      if (kk < C2_) v = AL[(i64)row*C2_ + kk]*amean[(i64)bb*C2_ + kk];
      At[i][r] = v;
    }
    for (int idx = tid; idx < 9216; idx += 256){
      int c = idx >> 6, i = idx & 63;
      int kk = k0 + i;
      float v = 0.f;
      if (c < E1_ && kk < C2_) v = w_g1[(i64)c*C2_ + kk];
      Bt[i][c] = v;
    }
    __syncthreads();
    if (tid < 224){
      for (int i = 0; i < 64; i++){
        F4 a = *(F4*)&At[i][r0];
        float bv[10];
        #pragma unroll
        for (int u = 0; u < 5; u++){
          F2 b2 = *(F2*)&Bt[i][cc0 + u*2];
          bv[u*2] = b2.v[0]; bv[u*2+1] = b2.v[1];
        }
        #pragma unroll
        for (int ri = 0; ri < 4; ri++)
          #pragma unroll
          for (int ci = 0; ci < 10; ci++)
            acc[ri][ci] += a.v[ri]*bv[ci];
      }
    }
    __syncthreads();
  }
  if (tid < 224){
    #pragma unroll
    for (int ri = 0; ri < 4; ri++)
      #pragma unroll
      for (int ci = 0; ci < 10; ci++){
        int c = cc0 + ci;
        if (c < E1_) atomicAdd(&e[(i64)(mt*64 + r0 + ri)*E1_ + c], acc[ri][ci]);
      }
  }
}

// ---------------- BN stats -> coefA/coefB (b_g1 absorbed by BN) ----------------
__global__ void k_bnstats(const float* __restrict__ e, const float* __restrict__ bn_g,
                          const float* __restrict__ bn_b, float* cA, float* cB){
  __shared__ float s1a[256], s2a[256];
  int c = blockIdx.x, tid = threadIdx.x;
  float s1 = 0.f, s2 = 0.f;
  for (int row = tid; row < B_*T_; row += 256){
    float v = e[(i64)row*E1_ + c];
    s1 += v; s2 += v*v;
  }
  s1a[tid] = s1; s2a[tid] = s2; __syncthreads();
  for (int s = 128; s > 0; s >>= 1){
    if (tid < s){ s1a[tid] += s1a[tid+s]; s2a[tid] += s2a[tid+s]; }
    __syncthreads();
  }
  if (tid == 0){
    float n = (float)(B_*T_);
    float mu = s1a[0]/n;
    float var = s2a[0]/n - mu*mu;
    float a = bn_g[c]/sqrtf(var + 1e-5f);
    cA[c] = a; cB[c] = bn_b[c] - mu*a;
  }
}

// ---------------- a_pre = relu(BN(e)) @ w_g2^T -> relu(+b_g2) . w_g3 (fused, atomics) ---
__global__ __launch_bounds__(128) void k_gemm2(const float* __restrict__ e,
                                               const float* __restrict__ cA, const float* __restrict__ cB,
                                               const float* __restrict__ g2t,
                                               const float* __restrict__ b_g2, const float* __restrict__ w_g3,
                                               float* __restrict__ apre){
  __shared__ __align__(16) float At2[140][68];
  int mt = blockIdx.x/30, nc = blockIdx.x%30;
  int tid = threadIdx.x;
  int nbase = nc*48;
  for (int idx = tid; idx < 64*140; idx += 128){
    int r = idx/140, k = idx - r*140;
    float v = e[(i64)(mt*64 + r)*E1_ + k]*cA[k] + cB[k];
    At2[k][r] = fmaxf(v, 0.f);
  }
  __syncthreads();
  if (tid < 96){
    int rg = tid/6, ng = tid%6;
    int r0 = rg*4, n0 = nbase + ng*8;
    float acc[4][8];
    #pragma unroll
    for (int ri = 0; ri < 4; ri++)
      #pragma unroll
      for (int ni = 0; ni < 8; ni++) acc[ri][ni] = 0.f;
    for (int k = 0; k < E1_; k++){
      F4 a = *(F4*)&At2[k][r0];
      float bvv[8];
      if (n0 + 8 <= E2_){
        F4 b0 = *(const F4*)&g2t[(i64)k*E2_ + n0];
        F4 b1 = *(const F4*)&g2t[(i64)k*E2_ + n0 + 4];
        #pragma unroll
        for (int u = 0; u < 4; u++){ bvv[u] = b0.v[u]; bvv[u+4] = b1.v[u]; }
      } else {
        #pragma unroll
        for (int ni = 0; ni < 8; ni++){ int n = n0+ni; bvv[ni] = (n < E2_) ? g2t[(i64)k*E2_ + n] : 0.f; }
      }
      #pragma unroll
      for (int ri = 0; ri < 4; ri++)
        #pragma unroll
        for (int ni = 0; ni < 8; ni++) acc[ri][ni] += a.v[ri]*bvv[ni];
    }
    #pragma unroll
    for (int ri = 0; ri < 4; ri++){
      float s = 0.f;
      #pragma unroll
      for (int ni = 0; ni < 8; ni++){
        int n = n0 + ni;
        if (n < E2_){
          float a2 = acc[ri][ni] + b_g2[n];
          if (a2 > 0.f) s += a2*w_g3[n];
        }
      }
      atomicAdd(&apre[mt*64 + r0 + ri], s);
    }
  }
}

// ---------------- softmax over T (b_g3 absorbed) + logits init ----------------
__global__ void k_soft(const float* __restrict__ apre, const float* __restrict__ b_clf,
                       float* __restrict__ wa, float* __restrict__ out){
  __shared__ float sr[256];
  int b = blockIdx.x, tid = threadIdx.x;
  float v = (tid < T_) ? apre[b*T_ + tid] : -3.4e38f;
  sr[tid] = v; __syncthreads();
  for (int s = 128; s > 0; s >>= 1){ if (tid < s) sr[tid] = fmaxf(sr[tid], sr[tid+s]); __syncthreads(); }
  float mx = sr[0]; __syncthreads();
  float ev = (tid < T_) ? __expf(v - mx) : 0.f;
  sr[tid] = ev; __syncthreads();
  for (int s = 128; s > 0; s >>= 1){ if (tid < s) sr[tid] += sr[tid+s]; __syncthreads(); }
  float den = sr[0];
  if (tid < T_) wa[b*T_ + tid] = ev/den;
  if (b == 0 && tid < 2*B_) out[tid] = b_clf[tid & 1];
}

// ---------------- dnc = sum_t align*a ; logits += dnc @ w_clf^T ----------------
__global__ void k_dnc(const float* __restrict__ AL, const float* __restrict__ wa,
                      const float* __restrict__ w_clf, float* __restrict__ out){
  int b = blockIdx.x/11, ch = blockIdx.x%11;
  int c2 = ch*256 + threadIdx.x;
  float acc = 0.f;
  if (c2 < C2_){
    for (int t = 0; t < T_; t++)
      acc += AL[(i64)(b*T_ + t)*C2_ + c2]*wa[b*T_ + t];
    out[96 + (i64)b*C2_ + c2] = acc;
  }
  float p0 = (c2 < C2_) ? acc*w_clf[c2]        : 0.f;
  float p1 = (c2 < C2_) ? acc*w_clf[C2_ + c2]  : 0.f;
  p0 = wredsum(p0); p1 = wredsum(p1);
  if ((threadIdx.x & 63) == 0){
    atomicAdd(&out[b*2 + 0], p0);
    atomicAdd(&out[b*2 + 1], p1);
  }
}

extern "C" void kernel_launch(void* const* d_in, const int* in_sizes, int n_in,
                              void* d_out, int out_size, void* d_ws, size_t ws_size,
                              hipStream_t stream){
  const float* x     = (const float*)d_in[0];
  const float* emb_w = (const float*)d_in[1];
  const float* emb_b = (const float*)d_in[2];
  const float* w_ih  = (const float*)d_in[3];
  const float* w_hh  = (const float*)d_in[4];
  const float* b_ih  = (const float*)d_in[5];
  const float* b_hh  = (const float*)d_in[6];
  const float* wq    = (const float*)d_in[7];
  const float* bq    = (const float*)d_in[8];
  const float* wk    = (const float*)d_in[9];
  const float* bk    = (const float*)d_in[10];
  const float* wv_in = (const float*)d_in[11];
  const float* bv    = (const float*)d_in[12];
  const float* u0    = (const float*)d_in[13];
  const float* w_g1  = (const float*)d_in[14];
  const float* bn_g  = (const float*)d_in[16];
  const float* bn_b  = (const float*)d_in[17];
  const float* w_g2  = (const float*)d_in[18];
  const float* b_g2  = (const float*)d_in[19];
  const float* w_g3  = (const float*)d_in[20];
  const float* w_clf = (const float*)d_in[22];
  const float* b_clf = (const float*)d_in[23];
  float* out = (float*)d_out;
  float* W = (float*)d_ws;

  float* wsig   = W + OFF_SIGMA;
  float* whhT   = W + OFF_WHHT;
  float* wzv    = W + OFF_WZV;
  float* wuv    = W + OFF_WUV;
  float* wp     = W + OFF_P;
  float* wr0    = W + OFF_R0;
  float* wM     = W + OFF_MM;
  float* wM2    = W + OFF_M2;
  float* wM4    = W + OFF_M4;
  float* wM5    = W + OFF_M5;
  float* wamean = W + OFF_AMEAN;
  float* we     = W + OFF_E;
  float* wcA    = W + OFF_CA;
  float* wcB    = W + OFF_CB;
  float* wapre  = W + OFF_APRE;
  float* wa     = W + OFF_A;
  float* wg2t   = W + OFF_G2T;

  float* outAL = out + 96 + (i64)B_*C2_;  // align region

  hipMemsetAsync(we, 0, (size_t)(B_*T_)*E1_*sizeof(float), stream);
  hipMemsetAsync(wapre, 0, (size_t)(B_*T_)*sizeof(float), stream);

  k_prep1<<<96, 256, 0, stream>>>(w_hh, wq, wk, wv_in, w_ih, emb_w, emb_b, b_ih, bq, bk,
                                  w_g2, whhT, wzv, wuv, wg2t, wp, wr0);
  k_prep2<<<1, 64, 0, stream>>>(wv_in, u0, wM, wM2, wM4, wM5, wsig);
  k_scan<<<B_, 512, 0, stream>>>(x, b_hh, bv, whhT, wzv, wuv, wp, wr0, wsig, outAL);
  k_amean<<<B_*11, 256, 0, stream>>>(outAL, wamean);
  k_gemm1<<<600, 256, 0, stream>>>(outAL, wamean, w_g1, we);
  k_bnstats<<<E1_, 256, 0, stream>>>(we, bn_g, bn_b, wcA, wcB);
  k_gemm2<<<150*30, 128, 0, stream>>>(we, wcA, wcB, wg2t, b_g2, w_g3, wapre);
  k_soft<<<B_, 256, 0, stream>>>(wapre, b_clf, wa, out);
  k_dnc<<<B_*11, 256, 0, stream>>>(outAL, wa, w_clf, out);
}

// Round 11
// 9767.458 us; speedup vs baseline: 1.0355x; 1.0355x over previous
//
#include <hip/hip_runtime.h>
#include <hip/hip_bf16.h>
#include <math.h>

// Problem dims
#define B_  48
#define T_  200
#define C_  53
#define H_  64
#define C2_ 2809
#define E1_ 140
#define E2_ 1404
#define TS  60          // padded LDS row stride (floats)

typedef long long i64;

struct __align__(16) F4 { float v[4]; };
struct __align__(8)  F2 { float v[2]; };

__device__ __forceinline__ float wredsum(float v){
  #pragma unroll
  for (int o = 32; o > 0; o >>= 1) v += __shfl_xor(v, o);
  return v;
}
__device__ __forceinline__ float sigm(float x){ return 1.f/(1.f + __expf(-x)); }
__device__ __forceinline__ float tanhx(float x){
  float a = fabsf(x);
  float e = __expf(-2.f*a);
  float t = (1.f - e)/(1.f + e);
  return copysignf(t, x);
}

// 2-row x 4-col eigen squaring tile: Y = (X@X)*inv, fused ssq/trace stats.
__device__ __forceinline__ void eig_mm(const float* __restrict__ X, float* __restrict__ Y,
                                       int r0, int c0, float inv,
                                       float& essq, float& etrc){
  float ea0[4] = {0.f,0.f,0.f,0.f};
  float ea1[4] = {0.f,0.f,0.f,0.f};
  for (int kq = 0; kq < 13; kq++){
    int k4 = kq*4;
    F4 a0 = *(const F4*)&X[(r0+0)*TS + k4];
    F4 a1 = *(const F4*)&X[(r0+1)*TS + k4];
    F4 b0 = *(const F4*)&X[(k4+0)*TS + c0];
    F4 b1 = *(const F4*)&X[(k4+1)*TS + c0];
    F4 b2 = *(const F4*)&X[(k4+2)*TS + c0];
    F4 b3 = *(const F4*)&X[(k4+3)*TS + c0];
    #pragma unroll
    for (int ci = 0; ci < 4; ci++){
      ea0[ci] += a0.v[0]*b0.v[ci] + a0.v[1]*b1.v[ci] + a0.v[2]*b2.v[ci] + a0.v[3]*b3.v[ci];
      ea1[ci] += a1.v[0]*b0.v[ci] + a1.v[1]*b1.v[ci] + a1.v[2]*b2.v[ci] + a1.v[3]*b3.v[ci];
    }
  }
  {
    float a0 = X[(r0+0)*TS + 52], a1 = X[(r0+1)*TS + 52];
    F4 bb = *(const F4*)&X[52*TS + c0];
    #pragma unroll
    for (int ci = 0; ci < 4; ci++){ ea0[ci] += a0*bb.v[ci]; ea1[ci] += a1*bb.v[ci]; }
  }
  F4 o0, o1;
  #pragma unroll
  for (int ci = 0; ci < 4; ci++){
    o0.v[ci] = ea0[ci]*inv;
    o1.v[ci] = ea1[ci]*inv;
    essq += o0.v[ci]*o0.v[ci] + o1.v[ci]*o1.v[ci];
  }
  if (r0   >= c0 && r0   < c0+4) etrc += o0.v[r0-c0];
  if (r0+1 >= c0 && r0+1 < c0+4) etrc += o1.v[r0+1-c0];
  *(F4*)&Y[(r0+0)*TS + c0] = o0;
  *(F4*)&Y[(r0+1)*TS + c0] = o1;
}

// 3-row x 4-col first squaring tile (rows r0..r0+2, r0<=51)
__device__ __forceinline__ void eig_mm3(const float* __restrict__ X, float* __restrict__ Y,
                                        int r0, int c0, float inv,
                                        float& essq, float& etrc){
  float ea0[4] = {0.f,0.f,0.f,0.f};
  float ea1[4] = {0.f,0.f,0.f,0.f};
  float ea2[4] = {0.f,0.f,0.f,0.f};
  for (int kq = 0; kq < 13; kq++){
    int k4 = kq*4;
    F4 a0 = *(const F4*)&X[(r0+0)*TS + k4];
    F4 a1 = *(const F4*)&X[(r0+1)*TS + k4];
    F4 a2 = *(const F4*)&X[(r0+2)*TS + k4];
    F4 b0 = *(const F4*)&X[(k4+0)*TS + c0];
    F4 b1 = *(const F4*)&X[(k4+1)*TS + c0];
    F4 b2 = *(const F4*)&X[(k4+2)*TS + c0];
    F4 b3 = *(const F4*)&X[(k4+3)*TS + c0];
    #pragma unroll
    for (int ci = 0; ci < 4; ci++){
      ea0[ci] += a0.v[0]*b0.v[ci] + a0.v[1]*b1.v[ci] + a0.v[2]*b2.v[ci] + a0.v[3]*b3.v[ci];
      ea1[ci] += a1.v[0]*b0.v[ci] + a1.v[1]*b1.v[ci] + a1.v[2]*b2.v[ci] + a1.v[3]*b3.v[ci];
      ea2[ci] += a2.v[0]*b0.v[ci] + a2.v[1]*b1.v[ci] + a2.v[2]*b2.v[ci] + a2.v[3]*b3.v[ci];
    }
  }
  {
    float a0 = X[(r0+0)*TS + 52], a1 = X[(r0+1)*TS + 52], a2 = X[(r0+2)*TS + 52];
    F4 bb = *(const F4*)&X[52*TS + c0];
    #pragma unroll
    for (int ci = 0; ci < 4; ci++){
      ea0[ci] += a0*bb.v[ci]; ea1[ci] += a1*bb.v[ci]; ea2[ci] += a2*bb.v[ci];
    }
  }
  F4 o0, o1, o2;
  #pragma unroll
  for (int ci = 0; ci < 4; ci++){
    o0.v[ci] = ea0[ci]*inv;
    o1.v[ci] = ea1[ci]*inv;
    o2.v[ci] = ea2[ci]*inv;
    essq += o0.v[ci]*o0.v[ci] + o1.v[ci]*o1.v[ci] + o2.v[ci]*o2.v[ci];
  }
  if (r0   >= c0 && r0   < c0+4) etrc += o0.v[r0-c0];
  if (r0+1 >= c0 && r0+1 < c0+4) etrc += o1.v[r0+1-c0];
  if (r0+2 >= c0 && r0+2 < c0+4) etrc += o2.v[r0+2-c0];
  *(F4*)&Y[(r0+0)*TS + c0] = o0;
  *(F4*)&Y[(r0+1)*TS + c0] = o1;
  *(F4*)&Y[(r0+2)*TS + c0] = o2;
}

// ---------------- ws layout (float offsets) ----------------
#define OFF_SIGMA 0
#define OFF_WHHT  200
#define OFF_WZV   12488
#define OFF_WUV   20680
#define OFF_P     20812
#define OFF_R0    21004
#define OFF_MM    21196
#define OFF_M2    25292
#define OFF_M4    29388
#define OFF_M5    33484
#define OFF_AMEAN 37580
#define OFF_E     172412
#define OFF_CA    1516412
#define OFF_CB    1516552
#define OFF_APRE  1516692
#define OFF_A     1526292
#define OFF_G2T   1535892

// ---------------- prep1: transposes + G=Wq^T Wk + u-vectors + p/r0 ----------------
__global__ void k_prep1(const float* __restrict__ w_hh, const float* __restrict__ wq,
                        const float* __restrict__ wk, const float* __restrict__ wv,
                        const float* __restrict__ w_ih, const float* __restrict__ emb_w,
                        const float* __restrict__ emb_b, const float* __restrict__ b_ih,
                        const float* __restrict__ bq, const float* __restrict__ bk,
                        const float* __restrict__ w_g2,
                        float* whhT, float* wzv, float* wuv, float* g2t,
                        float* p, float* r0){
  int idx0 = blockIdx.x*blockDim.x + threadIdx.x;
  int stride = gridDim.x*blockDim.x;
  for (int i = idx0; i < 64*192; i += stride){
    int kk = i/192, g = i%192;
    whhT[i] = w_hh[g*64 + kk];
  }
  // wzv[h][0..63] = G[h][a] = sum_m wq[m][h]*wk[m][a]; wzv[h][64..127] = wv[a][h]
  for (int i = idx0; i < 8192; i += stride){
    int h = i >> 7, a = i & 127;
    if (a < 64){
      float g = 0.f;
      for (int m = 0; m < 64; m++) g += wq[m*64 + h]*wk[m*64 + a];
      wzv[i] = g;
    } else {
      wzv[i] = wv[(a-64)*64 + h];
    }
  }
  for (int i = idx0; i < 129; i += stride){
    if (i < 64){
      float s = 0.f;
      for (int m = 0; m < 64; m++) s += wq[m*64 + i]*bk[m];
      wuv[i] = s;
    } else if (i < 128){
      int h = i - 64;
      float s = 0.f;
      for (int m = 0; m < 64; m++) s += wk[m*64 + h]*bq[m];
      wuv[i] = s;
    } else {
      float s = 0.f;
      for (int m = 0; m < 64; m++) s += bq[m]*bk[m];
      wuv[128] = s;
    }
  }
  for (int i = idx0; i < 140*1404; i += stride){ int k = i/1404, n = i%1404; g2t[i] = w_g2[n*140+k]; }
  for (int i = idx0; i < 192; i += stride){
    float s1 = 0.f, s2 = 0.f;
    for (int e = 0; e < 32; e++){ float w = w_ih[i*32+e]; s1 += w*emb_w[e]; s2 += w*emb_b[e]; }
    p[i] = s1; r0[i] = s2 + b_ih[i];
  }
}

// ---------------- prep2: M powers + sigma[t] (serial power iteration) ----------------
__global__ void k_prep2(const float* __restrict__ wv, const float* __restrict__ u0,
                        float* Wm, float* Wm2, float* Wm4, float* Wm5, float* sigma){
  int r = threadIdx.x; // 64 threads, one wave
  for (int c = 0; c < 64; c++){
    float s = 0.f;
    for (int k = 0; k < 64; k++) s += wv[r*64+k]*wv[c*64+k];
    Wm[r*64+c] = s;
  }
  __syncthreads();
  for (int c = 0; c < 64; c++){
    float s = 0.f;
    for (int k = 0; k < 64; k++) s += Wm[r*64+k]*Wm[k*64+c];
    Wm2[r*64+c] = s;
  }
  __syncthreads();
  for (int c = 0; c < 64; c++){
    float s = 0.f;
    for (int k = 0; k < 64; k++) s += Wm2[r*64+k]*Wm2[k*64+c];
    Wm4[r*64+c] = s;
  }
  __syncthreads();
  for (int c = 0; c < 64; c++){
    float s = 0.f;
    for (int k = 0; k < 64; k++) s += Wm4[r*64+k]*Wm[k*64+c];
    Wm5[r*64+c] = s;
  }
  __syncthreads();
  __shared__ float su[64];
  su[r] = u0[r];
  __syncthreads();
  for (int t = 0; t < T_; t++){
    float z = 0.f, w = 0.f;
    for (int k = 0; k < 64; k++){ float uk = su[k]; z += Wm4[r*64+k]*uk; w += Wm5[r*64+k]*uk; }
    float nw = wredsum(w*w);
    float zw = wredsum(z*w);
    float sg = sqrtf(nw / fmaxf(zw, 1e-35f));
    if (r == 0) sigma[t] = sg;
    float wn = w * (1.f/sqrtf(fmaxf(nw, 1e-35f)));
    __syncthreads();
    su[r] = wn;
    __syncthreads();
  }
}

// ---------------- the scan: one WG per batch, all 200 steps on-chip ----------------
// r9 base + D-merge with WAVE-ALIGNED split (h_raw on waves 0-3, X1 on waves 4-7;
// no wave executes two bodies) + J>=3 exit + wave-aligned F split.
__global__ __launch_bounds__(512, 1) void k_scan(
    const float* __restrict__ x, const float* __restrict__ b_hh,
    const float* __restrict__ bv,
    const float* __restrict__ whhT, const float* __restrict__ wzv,
    const float* __restrict__ wuv,
    const float* __restrict__ wp, const float* __restrict__ wr0,
    const float* __restrict__ sigma, float* __restrict__ outAL){
  __shared__ __align__(16) float L[19056];
  float* Rh  = L;            // [64][60] h (persistent); raw h_raw during E
  float* R4  = L + 3840;     // [64][60] hg -> eigen pong
  float* R3  = L + 7680;     // [64][60] ZT -> eigen ping
  float* R2  = L + 11520;    // [53][64] val (dead after D)
  float* R1  = L + 14912;    // [56][60] S (preserved all step)
  float* Lp  = L + 18272;    // 192
  float* Lr0 = L + 18464;    // 192
  float* Lbh = L + 18656;    // 192
  float* Lbv = L + 18848;    // 64
  float* Lrq = L + 18912;    // 56
  float* Lrk = L + 18968;    // 56
  float* Lsc = L + 19024;    // 32: [2j]=ssq_j, [2j+1]=tr_j
  int tid = threadIdx.x;
  int b = blockIdx.x;

  for (int i = tid; i < 192; i += 512){ Lp[i] = wp[i]; Lr0[i] = wr0[i]; Lbh[i] = b_hh[i]; }
  for (int i = tid; i < 64; i += 512) Lbv[i] = bv[i];
  for (int i = tid; i < 18272; i += 512) L[i] = 0.f;  // zero Rh..R1 (h0=0, pads)
  __syncthreads();

  int ct4 = tid >> 4, jt4 = tid & 15;   // 224-thread tilings (GH / h_raw)
  int c0g = ct4*4, j0g = jt4*4;
  int it14 = tid/14, jt14 = tid%14;     // 196-thread scores tiling
  int i0s = it14*4, j0s = jt14*4;
  int ctq = tid >> 5, gtq = tid & 31;   // 448-thread QKV tiling
  int c0q = ctq*4, g0q = gtq*4;
  int erg = tid/14, ecg = tid%14;       // 378-thread eigen tiling (2x4)
  int er0 = erg*2, ec0 = ecg*4;

  const float c0v = wuv[128];

  for (int t = 0; t < T_; t++){
    // ---- A: GH + gates fused: gh = h @ w_hh^T (+b_hh); hg -> R4 (224 thr) ----
    if (tid < 32) Lsc[tid] = 0.f;
    if (tid < 224){
      float gacc[3][4][4];
      #pragma unroll
      for (int g = 0; g < 3; g++)
        #pragma unroll
        for (int ji = 0; ji < 4; ji++){
          float bb = Lbh[g*64 + j0g + ji];
          #pragma unroll
          for (int ci = 0; ci < 4; ci++) gacc[g][ji][ci] = bb;
        }
      for (int kk = 0; kk < 64; kk++){
        F4 hv = *(F4*)&Rh[kk*TS + c0g];
        F4 w0 = *(const F4*)&whhT[kk*192 + j0g];
        F4 w1 = *(const F4*)&whhT[kk*192 + 64 + j0g];
        F4 w2 = *(const F4*)&whhT[kk*192 + 128 + j0g];
        #pragma unroll
        for (int ji = 0; ji < 4; ji++)
          #pragma unroll
          for (int ci = 0; ci < 4; ci++){
            gacc[0][ji][ci] += hv.v[ci]*w0.v[ji];
            gacc[1][ji][ci] += hv.v[ci]*w1.v[ji];
            gacc[2][ji][ci] += hv.v[ci]*w2.v[ji];
          }
      }
      float xv[4];
      #pragma unroll
      for (int ci = 0; ci < 4; ci++){
        int c = c0g + ci;
        xv[ci] = (c < C_) ? x[(i64)(b*T_ + t)*C_ + c] : 0.f;
      }
      F4 p0 = *(F4*)&Lp[j0g], p1 = *(F4*)&Lp[64+j0g], p2 = *(F4*)&Lp[128+j0g];
      F4 q0 = *(F4*)&Lr0[j0g], q1 = *(F4*)&Lr0[64+j0g], q2 = *(F4*)&Lr0[128+j0g];
      #pragma unroll
      for (int ji = 0; ji < 4; ji++){
        F4 hold = *(F4*)&Rh[(j0g+ji)*TS + c0g];
        F4 o;
        #pragma unroll
        for (int ci = 0; ci < 4; ci++){
          float rr = sigm(xv[ci]*p0.v[ji] + q0.v[ji] + gacc[0][ji][ci]);
          float zz = sigm(xv[ci]*p1.v[ji] + q1.v[ji] + gacc[1][ji][ci]);
          float nn = tanhx(xv[ci]*p2.v[ji] + q2.v[ji] + rr*gacc[2][ji][ci]);
          float hg = (1.f - zz)*nn + zz*hold.v[ci];
          o.v[ci] = (c0g + ci < C_) ? hg : 0.f;
        }
        *(F4*)&R4[(j0g+ji)*TS + c0g] = o;
      }
    }
    __syncthreads();
    // ---- B: projections: ZT = (hg G)^T -> R3, val -> R2 (448); rank-1 vecs ----
    if (tid < 448){
      float acc[4][4];
      #pragma unroll
      for (int gi = 0; gi < 4; gi++)
        #pragma unroll
        for (int ci = 0; ci < 4; ci++) acc[gi][ci] = 0.f;
      for (int kk = 0; kk < 64; kk++){
        F4 a = *(F4*)&R4[kk*TS + c0q];
        F4 w = *(const F4*)&wzv[kk*128 + g0q];
        #pragma unroll
        for (int gi = 0; gi < 4; gi++)
          #pragma unroll
          for (int ci = 0; ci < 4; ci++) acc[gi][ci] += a.v[ci]*w.v[gi];
      }
      if (g0q < 64){
        #pragma unroll
        for (int gi = 0; gi < 4; gi++){
          F4 o;
          #pragma unroll
          for (int ci = 0; ci < 4; ci++) o.v[ci] = acc[gi][ci];
          *(F4*)&R3[(g0q+gi)*TS + c0q] = o;
        }
      } else {
        float invs = 1.f/sigma[t];
        int a0i = g0q - 64;
        #pragma unroll
        for (int ci = 0; ci < 4; ci++){
          int c = c0q + ci;
          if (c < C_){
            F4 o;
            #pragma unroll
            for (int gi = 0; gi < 4; gi++) o.v[gi] = acc[gi][ci]*invs + Lbv[a0i+gi];
            *(F4*)&R2[c*64 + a0i] = o;
          }
        }
      }
    } else if (tid < 504){
      int u = tid - 448;
      float rq = 0.f, rk = 0.f;
      if (u < C_){
        for (int h = 0; h < 64; h++){
          float hv = R4[h*TS + u];
          rq += hv*wuv[h];
          rk += hv*wuv[64+h];
        }
      }
      if (u < 56){ Lrq[u] = rq; Lrk[u] = rk; }
    }
    __syncthreads();
    // ---- C: scores S = ZT^T.hgT + rank1 -> R1 (196 thr, 4x4); stats ----
    {
      float sacc[4][4];
      float ssq = 0.f, trc = 0.f;
      if (tid < 196){
        #pragma unroll
        for (int ii = 0; ii < 4; ii++)
          #pragma unroll
          for (int jj = 0; jj < 4; jj++){
            int i = i0s + ii, j = j0s + jj;
            sacc[ii][jj] = (i < C_ && j < C_) ? (Lrq[i] + Lrk[j] + c0v) : 0.f;
          }
        for (int aq = 0; aq < 16; aq++){
          int a4 = aq*4;
          F4 qa0 = *(F4*)&R3[(a4+0)*TS + i0s];
          F4 qa1 = *(F4*)&R3[(a4+1)*TS + i0s];
          F4 qa2 = *(F4*)&R3[(a4+2)*TS + i0s];
          F4 qa3 = *(F4*)&R3[(a4+3)*TS + i0s];
          F4 kb0 = *(F4*)&R4[(a4+0)*TS + j0s];
          F4 kb1 = *(F4*)&R4[(a4+1)*TS + j0s];
          F4 kb2 = *(F4*)&R4[(a4+2)*TS + j0s];
          F4 kb3 = *(F4*)&R4[(a4+3)*TS + j0s];
          #pragma unroll
          for (int ii = 0; ii < 4; ii++)
            #pragma unroll
            for (int jj = 0; jj < 4; jj++)
              sacc[ii][jj] += qa0.v[ii]*kb0.v[jj] + qa1.v[ii]*kb1.v[jj]
                            + qa2.v[ii]*kb2.v[jj] + qa3.v[ii]*kb3.v[jj];
        }
        #pragma unroll
        for (int ii = 0; ii < 4; ii++){
          int i = i0s + ii;
          if (i < C_){
            F4 o;
            #pragma unroll
            for (int jj = 0; jj < 4; jj++){
              o.v[jj] = sacc[ii][jj];
              ssq += sacc[ii][jj]*sacc[ii][jj];
            }
            *(F4*)&R1[i*TS + j0s] = o;
            if (j0s <= i && i < j0s + 4) trc += sacc[ii][i - j0s];
          }
        }
      }
      ssq = wredsum(ssq); trc = wredsum(trc);
      if ((tid & 63) == 0){
        if (ssq != 0.f) atomicAdd(&Lsc[0], ssq);
        if (trc != 0.f) atomicAdd(&Lsc[1], trc);
      }
    }
    __syncthreads();
    // ---- D (wave-aligned): h_raw RAW -> Rh (waves 0-3, 224 thr)
    //       || X1 = S@S/ssq0 -> R3 (waves 4-7, 252 thr at tid 256..507) ----
    {
      float essq = 0.f, etrc = 0.f;
      if (tid < 224){
        float hr0[4] = {0.f,0.f,0.f,0.f};
        float hr1[4] = {0.f,0.f,0.f,0.f};
        float hr2[4] = {0.f,0.f,0.f,0.f};
        float hr3[4] = {0.f,0.f,0.f,0.f};
        for (int kq = 0; kq < 13; kq++){
          int k4 = kq*4;
          F4 a0 = *(F4*)&R1[(c0g+0)*TS + k4];
          F4 a1 = *(F4*)&R1[(c0g+1)*TS + k4];
          F4 a2 = *(F4*)&R1[(c0g+2)*TS + k4];
          F4 a3 = *(F4*)&R1[(c0g+3)*TS + k4];
          F4 b0 = *(F4*)&R2[(k4+0)*64 + j0g];
          F4 b1 = *(F4*)&R2[(k4+1)*64 + j0g];
          F4 b2 = *(F4*)&R2[(k4+2)*64 + j0g];
          F4 b3 = *(F4*)&R2[(k4+3)*64 + j0g];
          #pragma unroll
          for (int jj = 0; jj < 4; jj++){
            hr0[jj] += a0.v[0]*b0.v[jj] + a0.v[1]*b1.v[jj] + a0.v[2]*b2.v[jj] + a0.v[3]*b3.v[jj];
            hr1[jj] += a1.v[0]*b0.v[jj] + a1.v[1]*b1.v[jj] + a1.v[2]*b2.v[jj] + a1.v[3]*b3.v[jj];
            hr2[jj] += a2.v[0]*b0.v[jj] + a2.v[1]*b1.v[jj] + a2.v[2]*b2.v[jj] + a2.v[3]*b3.v[jj];
            hr3[jj] += a3.v[0]*b0.v[jj] + a3.v[1]*b1.v[jj] + a3.v[2]*b2.v[jj] + a3.v[3]*b3.v[jj];
          }
        }
        {
          const int k = 52;
          float a0 = R1[(c0g+0)*TS + k], a1 = R1[(c0g+1)*TS + k];
          float a2 = R1[(c0g+2)*TS + k], a3 = R1[(c0g+3)*TS + k];
          F4 bb = *(F4*)&R2[k*64 + j0g];
          #pragma unroll
          for (int jj = 0; jj < 4; jj++){
            hr0[jj] += a0*bb.v[jj];
            hr1[jj] += a1*bb.v[jj];
            hr2[jj] += a2*bb.v[jj];
            hr3[jj] += a3*bb.v[jj];
          }
        }
        #pragma unroll
        for (int jj = 0; jj < 4; jj++){
          F4 o;
          o.v[0] = (c0g + 0 < C_) ? hr0[jj] : 0.f;
          o.v[1] = (c0g + 1 < C_) ? hr1[jj] : 0.f;
          o.v[2] = (c0g + 2 < C_) ? hr2[jj] : 0.f;
          o.v[3] = (c0g + 3 < C_) ? hr3[jj] : 0.f;
          *(F4*)&Rh[(j0g+jj)*TS + c0g] = o;   // RAW; scaled by invm in phase F
        }
      } else if (tid >= 256 && tid < 508){
        float inv0 = 1.f/fmaxf(Lsc[0], 1e-35f);
        int u = tid - 256;
        int r0e = (u/14)*3, c0e = (u%14)*4;
        eig_mm3(R1, R3, r0e, c0e, inv0, essq, etrc);
      }
      essq = wredsum(essq); etrc = wredsum(etrc);
      if ((tid & 63) == 0){
        if (essq != 0.f) atomicAdd(&Lsc[2], essq);
        if (etrc != 0.f) atomicAdd(&Lsc[3], etrc);
      }
    }
    __syncthreads();
    // ---- E: eigen squaring chain, fused stats (exit floor J>=3, conv-gated) ----
    float Gacc = 0.f, prevest = 1e30f, est = 0.f;
    int cnt = 0;
    float pssq = fmaxf(Lsc[0], 1e-35f), ptr1 = Lsc[1];
    float* Xb = R3; float* Yb = R4;
    for (int j = 2; j <= 13; j++){
      float sj = fmaxf(Lsc[2*(j-1)], 1e-35f);
      float tj = Lsc[2*(j-1)+1];
      int J = j - 2;
      float t1n = ptr1/sqrtf(pssq);
      float t2n = tj;
      float disc = 2.f*t2n - t1n*t1n;
      float rq = (disc >= 0.f) ? 0.5f*(fabsf(t1n) + sqrtf(disc))
                               : sqrtf(fmaxf(0.5f*(t1n*t1n - t2n), 1e-30f));
      rq = fminf(fmaxf(rq, 0.02f), 1.5f);
      est = Gacc + ldexpf(0.5f*log2f(pssq) + log2f(rq), -J);
      if (fabsf(est - prevest) < 1e-4f) cnt++; else cnt = 0;
      prevest = est;
      Gacc += ldexpf(log2f(pssq), -(J+1));
      if ((J >= 3 && cnt >= 1) || j == 13) break;
      pssq = sj; ptr1 = tj;
      {
        float inv = 1.f/sj;
        float essq = 0.f, etrc = 0.f;
        if (tid < 378) eig_mm(Xb, Yb, er0, ec0, inv, essq, etrc);
        essq = wredsum(essq); etrc = wredsum(etrc);
        if ((tid & 63) == 0){
          if (essq != 0.f) atomicAdd(&Lsc[2*j], essq);
          if (etrc != 0.f) atomicAdd(&Lsc[2*j+1], etrc);
        }
      }
      { float* tp = Xb; Xb = Yb; Yb = tp; }
      __syncthreads();
    }
    float invm = exp2f(-est);
    // ---- F (wave-aligned): h' = hraw*invm (waves 0-1) ; align write (waves 2-5) ----
    if (tid < 128){
      for (int idx = tid; idx < 960; idx += 128){
        F4 v = *(F4*)&Rh[idx*4];
        #pragma unroll
        for (int u = 0; u < 4; u++) v.v[u] *= invm;
        *(F4*)&Rh[idx*4] = v;
      }
    } else if (tid < 324){
      int u = tid - 128;
      int i0 = (u/14)*4, j0 = (u%14)*4;
      float* ALrow = outAL + (i64)(b*T_ + t)*C2_;
      #pragma unroll
      for (int ii = 0; ii < 4; ii++){
        int i = i0 + ii;
        if (i < C_){
          F4 s = *(F4*)&R1[i*TS + j0];
          #pragma unroll
          for (int jj = 0; jj < 4; jj++){
            int jc = j0 + jj;
            if (jc < C_) ALrow[i*C_ + jc] = s.v[jj]*invm;
          }
        }
      }
    }
    __syncthreads();
  }
}

// ---------------- amean: T-mean of (already scaled) align ----------------
__global__ void k_amean(const float* __restrict__ AL, float* __restrict__ amean){
  int b = blockIdx.x/11, ch = blockIdx.x%11;
  int c2 = ch*256 + threadIdx.x;
  if (c2 >= C2_) return;
  float acc = 0.f;
  for (int t = 0; t < T_; t++)
    acc += AL[(i64)(b*T_ + t)*C2_ + c2];
  amean[(i64)b*C2_ + c2] = acc*(1.f/(float)T_);
}

// ---------------- e = (align * mean) @ w_g1^T  (K-split x4, atomics, 256 thr) ------
__global__ __launch_bounds__(256) void k_gemm1(const float* __restrict__ AL,
                                               const float* __restrict__ amean,
                                               const float* __restrict__ w_g1,
                                               float* __restrict__ e){
  __shared__ __align__(16) float At[64][68];
  __shared__ __align__(16) float Bt[64][148];
  int mt = blockIdx.x >> 2, ks = blockIdx.x & 3;
  int tid = threadIdx.x;
  float acc[4][10];
  #pragma unroll
  for (int ri = 0; ri < 4; ri++)
    #pragma unroll
    for (int ci = 0; ci < 10; ci++) acc[ri][ci] = 0.f;
  int rg = tid/14, cg = tid%14;   // 224 compute threads: 16 row-groups x 14 col-groups
  int r0 = rg*4, cc0 = cg*10;
  for (int kb = 0; kb < 11; kb++){
    int k0 = (ks*11 + kb)*64;
    for (int idx = tid; idx < 4096; idx += 256){
      int r = idx >> 6, i = idx & 63;
      int kk = k0 + i;
      int row = mt*64 + r, bb = row/T_;
      float v = 0.f;
      if (kk < C2_) v = AL[(i64)row*C2_ + kk]*amean[(i64)bb*C2_ + kk];
      At[i][r] = v;
    }
    for (int idx = tid; idx < 9216; idx += 256){
      int c = idx >> 6, i = idx & 63;
      int kk = k0 + i;
      float v = 0.f;
      if (c < E1_ && kk < C2_) v = w_g1[(i64)c*C2_ + kk];
      Bt[i][c] = v;
    }
    __syncthreads();
    if (tid < 224){
      for (int i = 0; i < 64; i++){
        F4 a = *(F4*)&At[i][r0];
        float bv[10];
        #pragma unroll
        for (int u = 0; u < 5; u++){
          F2 b2 = *(F2*)&Bt[i][cc0 + u*2];
          bv[u*2] = b2.v[0]; bv[u*2+1] = b2.v[1];
        }
        #pragma unroll
        for (int ri = 0; ri < 4; ri++)
          #pragma unroll
          for (int ci = 0; ci < 10; ci++)
            acc[ri][ci] += a.v[ri]*bv[ci];
      }
    }
    __syncthreads();
  }
  if (tid < 224){
    #pragma unroll
    for (int ri = 0; ri < 4; ri++)
      #pragma unroll
      for (int ci = 0; ci < 10; ci++){
        int c = cc0 + ci;
        if (c < E1_) atomicAdd(&e[(i64)(mt*64 + r0 + ri)*E1_ + c], acc[ri][ci]);
      }
  }
}

// ---------------- BN stats -> coefA/coefB (b_g1 absorbed by BN) ----------------
__global__ void k_bnstats(const float* __restrict__ e, const float* __restrict__ bn_g,
                          const float* __restrict__ bn_b, float* cA, float* cB){
  __shared__ float s1a[256], s2a[256];
  int c = blockIdx.x, tid = threadIdx.x;
  float s1 = 0.f, s2 = 0.f;
  for (int row = tid; row < B_*T_; row += 256){
    float v = e[(i64)row*E1_ + c];
    s1 += v; s2 += v*v;
  }
  s1a[tid] = s1; s2a[tid] = s2; __syncthreads();
  for (int s = 128; s > 0; s >>= 1){
    if (tid < s){ s1a[tid] += s1a[tid+s]; s2a[tid] += s2a[tid+s]; }
    __syncthreads();
  }
  if (tid == 0){
    float n = (float)(B_*T_);
    float mu = s1a[0]/n;
    float var = s2a[0]/n - mu*mu;
    float a = bn_g[c]/sqrtf(var + 1e-5f);
    cA[c] = a; cB[c] = bn_b[c] - mu*a;
  }
}

// ---------------- a_pre = relu(BN(e)) @ w_g2^T -> relu(+b_g2) . w_g3 (fused, atomics) ---
__global__ __launch_bounds__(128) void k_gemm2(const float* __restrict__ e,
                                               const float* __restrict__ cA, const float* __restrict__ cB,
                                               const float* __restrict__ g2t,
                                               const float* __restrict__ b_g2, const float* __restrict__ w_g3,
                                               float* __restrict__ apre){
  __shared__ __align__(16) float At2[140][68];
  int mt = blockIdx.x/30, nc = blockIdx.x%30;
  int tid = threadIdx.x;
  int nbase = nc*48;
  for (int idx = tid; idx < 64*140; idx += 128){
    int r = idx/140, k = idx - r*140;
    float v = e[(i64)(mt*64 + r)*E1_ + k]*cA[k] + cB[k];
    At2[k][r] = fmaxf(v, 0.f);
  }
  __syncthreads();
  if (tid < 96){
    int rg = tid/6, ng = tid%6;
    int r0 = rg*4, n0 = nbase + ng*8;
    float acc[4][8];
    #pragma unroll
    for (int ri = 0; ri < 4; ri++)
      #pragma unroll
      for (int ni = 0; ni < 8; ni++) acc[ri][ni] = 0.f;
    for (int k = 0; k < E1_; k++){
      F4 a = *(F4*)&At2[k][r0];
      float bvv[8];
      if (n0 + 8 <= E2_){
        F4 b0 = *(const F4*)&g2t[(i64)k*E2_ + n0];
        F4 b1 = *(const F4*)&g2t[(i64)k*E2_ + n0 + 4];
        #pragma unroll
        for (int u = 0; u < 4; u++){ bvv[u] = b0.v[u]; bvv[u+4] = b1.v[u]; }
      } else {
        #pragma unroll
        for (int ni = 0; ni < 8; ni++){ int n = n0+ni; bvv[ni] = (n < E2_) ? g2t[(i64)k*E2_ + n] : 0.f; }
      }
      #pragma unroll
      for (int ri = 0; ri < 4; ri++)
        #pragma unroll
        for (int ni = 0; ni < 8; ni++) acc[ri][ni] += a.v[ri]*bvv[ni];
    }
    #pragma unroll
    for (int ri = 0; ri < 4; ri++){
      float s = 0.f;
      #pragma unroll
      for (int ni = 0; ni < 8; ni++){
        int n = n0 + ni;
        if (n < E2_){
          float a2 = acc[ri][ni] + b_g2[n];
          if (a2 > 0.f) s += a2*w_g3[n];
        }
      }
      atomicAdd(&apre[mt*64 + r0 + ri], s);
    }
  }
}

// ---------------- softmax over T (b_g3 absorbed) + logits init ----------------
__global__ void k_soft(const float* __restrict__ apre, const float* __restrict__ b_clf,
                       float* __restrict__ wa, float* __restrict__ out){
  __shared__ float sr[256];
  int b = blockIdx.x, tid = threadIdx.x;
  float v = (tid < T_) ? apre[b*T_ + tid] : -3.4e38f;
  sr[tid] = v; __syncthreads();
  for (int s = 128; s > 0; s >>= 1){ if (tid < s) sr[tid] = fmaxf(sr[tid], sr[tid+s]); __syncthreads(); }
  float mx = sr[0]; __syncthreads();
  float ev = (tid < T_) ? __expf(v - mx) : 0.f;
  sr[tid] = ev; __syncthreads();
  for (int s = 128; s > 0; s >>= 1){ if (tid < s) sr[tid] += sr[tid+s]; __syncthreads(); }
  float den = sr[0];
  if (tid < T_) wa[b*T_ + tid] = ev/den;
  if (b == 0 && tid < 2*B_) out[tid] = b_clf[tid & 1];
}

// ---------------- dnc = sum_t align*a ; logits += dnc @ w_clf^T ----------------
__global__ void k_dnc(const float* __restrict__ AL, const float* __restrict__ wa,
                      const float* __restrict__ w_clf, float* __restrict__ out){
  int b = blockIdx.x/11, ch = blockIdx.x%11;
  int c2 = ch*256 + threadIdx.x;
  float acc = 0.f;
  if (c2 < C2_){
    for (int t = 0; t < T_; t++)
      acc += AL[(i64)(b*T_ + t)*C2_ + c2]*wa[b*T_ + t];
    out[96 + (i64)b*C2_ + c2] = acc;
  }
  float p0 = (c2 < C2_) ? acc*w_clf[c2]        : 0.f;
  float p1 = (c2 < C2_) ? acc*w_clf[C2_ + c2]  : 0.f;
  p0 = wredsum(p0); p1 = wredsum(p1);
  if ((threadIdx.x & 63) == 0){
    atomicAdd(&out[b*2 + 0], p0);
    atomicAdd(&out[b*2 + 1], p1);
  }
}

extern "C" void kernel_launch(void* const* d_in, const int* in_sizes, int n_in,
                              void* d_out, int out_size, void* d_ws, size_t ws_size,
                              hipStream_t stream){
  const float* x     = (const float*)d_in[0];
  const float* emb_w = (const float*)d_in[1];
  const float* emb_b = (const float*)d_in[2];
  const float* w_ih  = (const float*)d_in[3];
  const float* w_hh  = (const float*)d_in[4];
  const float* b_ih  = (const float*)d_in[5];
  const float* b_hh  = (const float*)d_in[6];
  const float* wq    = (const float*)d_in[7];
  const float* bq    = (const float*)d_in[8];
  const float* wk    = (const float*)d_in[9];
  const float* bk    = (const float*)d_in[10];
  const float* wv_in = (const float*)d_in[11];
  const float* bv    = (const float*)d_in[12];
  const float* u0    = (const float*)d_in[13];
  const float* w_g1  = (const float*)d_in[14];
  const float* bn_g  = (const float*)d_in[16];
  const float* bn_b  = (const float*)d_in[17];
  const float* w_g2  = (const float*)d_in[18];
  const float* b_g2  = (const float*)d_in[19];
  const float* w_g3  = (const float*)d_in[20];
  const float* w_clf = (const float*)d_in[22];
  const float* b_clf = (const float*)d_in[23];
  float* out = (float*)d_out;
  float* W = (float*)d_ws;

  float* wsig   = W + OFF_SIGMA;
  float* whhT   = W + OFF_WHHT;
  float* wzv    = W + OFF_WZV;
  float* wuv    = W + OFF_WUV;
  float* wp     = W + OFF_P;
  float* wr0    = W + OFF_R0;
  float* wM     = W + OFF_MM;
  float* wM2    = W + OFF_M2;
  float* wM4    = W + OFF_M4;
  float* wM5    = W + OFF_M5;
  float* wamean = W + OFF_AMEAN;
  float* we     = W + OFF_E;
  float* wcA    = W + OFF_CA;
  float* wcB    = W + OFF_CB;
  float* wapre  = W + OFF_APRE;
  float* wa     = W + OFF_A;
  float* wg2t   = W + OFF_G2T;

  float* outAL = out + 96 + (i64)B_*C2_;  // align region

  hipMemsetAsync(we, 0, (size_t)(B_*T_)*E1_*sizeof(float), stream);
  hipMemsetAsync(wapre, 0, (size_t)(B_*T_)*sizeof(float), stream);

  k_prep1<<<96, 256, 0, stream>>>(w_hh, wq, wk, wv_in, w_ih, emb_w, emb_b, b_ih, bq, bk,
                                  w_g2, whhT, wzv, wuv, wg2t, wp, wr0);
  k_prep2<<<1, 64, 0, stream>>>(wv_in, u0, wM, wM2, wM4, wM5, wsig);
  k_scan<<<B_, 512, 0, stream>>>(x, b_hh, bv, whhT, wzv, wuv, wp, wr0, wsig, outAL);
  k_amean<<<B_*11, 256, 0, stream>>>(outAL, wamean);
  k_gemm1<<<600, 256, 0, stream>>>(outAL, wamean, w_g1, we);
  k_bnstats<<<E1_, 256, 0, stream>>>(we, bn_g, bn_b, wcA, wcB);
  k_gemm2<<<150*30, 128, 0, stream>>>(we, wcA, wcB, wg2t, b_g2, w_g3, wapre);
  k_soft<<<B_, 256, 0, stream>>>(wapre, b_clf, wa, out);
  k_dnc<<<B_*11, 256, 0, stream>>>(outAL, wa, w_clf, out);
}

// Round 12
// 8716.992 us; speedup vs baseline: 1.1603x; 1.1205x over previous
//
#include <hip/hip_runtime.h>
#include <hip/hip_bf16.h>
#include <math.h>

// Problem dims
#define B_  48
#define T_  200
#define C_  53
#define H_  64
#define C2_ 2809
#define E1_ 140
#define E2_ 1404
#define TS  60          // padded LDS row stride (floats)

typedef long long i64;

struct __align__(16) F4 { float v[4]; };
struct __align__(8)  F2 { float v[2]; };

__device__ __forceinline__ float wredsum(float v){
  #pragma unroll
  for (int o = 32; o > 0; o >>= 1) v += __shfl_xor(v, o);
  return v;
}
__device__ __forceinline__ float sigm(float x){ return 1.f/(1.f + __expf(-x)); }
__device__ __forceinline__ float tanhx(float x){
  float a = fabsf(x);
  float e = __expf(-2.f*a);
  float t = (1.f - e)/(1.f + e);
  return copysignf(t, x);
}

// 2-row x 4-col eigen squaring tile: Y = (X@X)*inv, fused ssq/trace stats.
// Reads a-rows r0,r0+1 (<=53, row 53 must be zero in X); writes unguarded
// (zero rows propagate, cleaning stale pads).
__device__ __forceinline__ void eig_mm(const float* __restrict__ X, float* __restrict__ Y,
                                       int r0, int c0, float inv,
                                       float& essq, float& etrc){
  float ea0[4] = {0.f,0.f,0.f,0.f};
  float ea1[4] = {0.f,0.f,0.f,0.f};
  for (int kq = 0; kq < 13; kq++){
    int k4 = kq*4;
    F4 a0 = *(const F4*)&X[(r0+0)*TS + k4];
    F4 a1 = *(const F4*)&X[(r0+1)*TS + k4];
    F4 b0 = *(const F4*)&X[(k4+0)*TS + c0];
    F4 b1 = *(const F4*)&X[(k4+1)*TS + c0];
    F4 b2 = *(const F4*)&X[(k4+2)*TS + c0];
    F4 b3 = *(const F4*)&X[(k4+3)*TS + c0];
    #pragma unroll
    for (int ci = 0; ci < 4; ci++){
      ea0[ci] += a0.v[0]*b0.v[ci] + a0.v[1]*b1.v[ci] + a0.v[2]*b2.v[ci] + a0.v[3]*b3.v[ci];
      ea1[ci] += a1.v[0]*b0.v[ci] + a1.v[1]*b1.v[ci] + a1.v[2]*b2.v[ci] + a1.v[3]*b3.v[ci];
    }
  }
  {
    float a0 = X[(r0+0)*TS + 52], a1 = X[(r0+1)*TS + 52];
    F4 bb = *(const F4*)&X[52*TS + c0];
    #pragma unroll
    for (int ci = 0; ci < 4; ci++){ ea0[ci] += a0*bb.v[ci]; ea1[ci] += a1*bb.v[ci]; }
  }
  F4 o0, o1;
  #pragma unroll
  for (int ci = 0; ci < 4; ci++){
    o0.v[ci] = ea0[ci]*inv;
    o1.v[ci] = ea1[ci]*inv;
    essq += o0.v[ci]*o0.v[ci] + o1.v[ci]*o1.v[ci];
  }
  if (r0   >= c0 && r0   < c0+4) etrc += o0.v[r0-c0];
  if (r0+1 >= c0 && r0+1 < c0+4) etrc += o1.v[r0+1-c0];
  *(F4*)&Y[(r0+0)*TS + c0] = o0;
  *(F4*)&Y[(r0+1)*TS + c0] = o1;
}

// ---------------- ws layout (float offsets) ----------------
#define OFF_SIGMA 0
#define OFF_WHHT  200
#define OFF_WZV   12488
#define OFF_WUV   20680
#define OFF_P     20812
#define OFF_R0    21004
#define OFF_MM    21196
#define OFF_M2    25292
#define OFF_M4    29388
#define OFF_M5    33484
#define OFF_AMEAN 37580
#define OFF_E     172412
#define OFF_CA    1516412
#define OFF_CB    1516552
#define OFF_APRE  1516692
#define OFF_A     1526292
#define OFF_G2T   1535892

// ---------------- prep1: transposes + G=Wq^T Wk + u-vectors + p/r0 ----------------
__global__ void k_prep1(const float* __restrict__ w_hh, const float* __restrict__ wq,
                        const float* __restrict__ wk, const float* __restrict__ wv,
                        const float* __restrict__ w_ih, const float* __restrict__ emb_w,
                        const float* __restrict__ emb_b, const float* __restrict__ b_ih,
                        const float* __restrict__ bq, const float* __restrict__ bk,
                        const float* __restrict__ w_g2,
                        float* whhT, float* wzv, float* wuv, float* g2t,
                        float* p, float* r0){
  int idx0 = blockIdx.x*blockDim.x + threadIdx.x;
  int stride = gridDim.x*blockDim.x;
  for (int i = idx0; i < 64*192; i += stride){
    int kk = i/192, g = i%192;
    whhT[i] = w_hh[g*64 + kk];
  }
  // wzv[h][0..63] = G[h][a] = sum_m wq[m][h]*wk[m][a]; wzv[h][64..127] = wv[a][h]
  for (int i = idx0; i < 8192; i += stride){
    int h = i >> 7, a = i & 127;
    if (a < 64){
      float g = 0.f;
      for (int m = 0; m < 64; m++) g += wq[m*64 + h]*wk[m*64 + a];
      wzv[i] = g;
    } else {
      wzv[i] = wv[(a-64)*64 + h];
    }
  }
  for (int i = idx0; i < 129; i += stride){
    if (i < 64){
      float s = 0.f;
      for (int m = 0; m < 64; m++) s += wq[m*64 + i]*bk[m];
      wuv[i] = s;
    } else if (i < 128){
      int h = i - 64;
      float s = 0.f;
      for (int m = 0; m < 64; m++) s += wk[m*64 + h]*bq[m];
      wuv[i] = s;
    } else {
      float s = 0.f;
      for (int m = 0; m < 64; m++) s += bq[m]*bk[m];
      wuv[128] = s;
    }
  }
  for (int i = idx0; i < 140*1404; i += stride){ int k = i/1404, n = i%1404; g2t[i] = w_g2[n*140+k]; }
  for (int i = idx0; i < 192; i += stride){
    float s1 = 0.f, s2 = 0.f;
    for (int e = 0; e < 32; e++){ float w = w_ih[i*32+e]; s1 += w*emb_w[e]; s2 += w*emb_b[e]; }
    p[i] = s1; r0[i] = s2 + b_ih[i];
  }
}

// ---------------- prep2: M powers + sigma[t] (serial power iteration) ----------------
__global__ void k_prep2(const float* __restrict__ wv, const float* __restrict__ u0,
                        float* Wm, float* Wm2, float* Wm4, float* Wm5, float* sigma){
  int r = threadIdx.x; // 64 threads, one wave
  for (int c = 0; c < 64; c++){
    float s = 0.f;
    for (int k = 0; k < 64; k++) s += wv[r*64+k]*wv[c*64+k];
    Wm[r*64+c] = s;
  }
  __syncthreads();
  for (int c = 0; c < 64; c++){
    float s = 0.f;
    for (int k = 0; k < 64; k++) s += Wm[r*64+k]*Wm[k*64+c];
    Wm2[r*64+c] = s;
  }
  __syncthreads();
  for (int c = 0; c < 64; c++){
    float s = 0.f;
    for (int k = 0; k < 64; k++) s += Wm2[r*64+k]*Wm2[k*64+c];
    Wm4[r*64+c] = s;
  }
  __syncthreads();
  for (int c = 0; c < 64; c++){
    float s = 0.f;
    for (int k = 0; k < 64; k++) s += Wm4[r*64+k]*Wm[k*64+c];
    Wm5[r*64+c] = s;
  }
  __syncthreads();
  __shared__ float su[64];
  su[r] = u0[r];
  __syncthreads();
  for (int t = 0; t < T_; t++){
    float z = 0.f, w = 0.f;
    for (int k = 0; k < 64; k++){ float uk = su[k]; z += Wm4[r*64+k]*uk; w += Wm5[r*64+k]*uk; }
    float nw = wredsum(w*w);
    float zw = wredsum(z*w);
    float sg = sqrtf(nw / fmaxf(zw, 1e-35f));
    if (r == 0) sigma[t] = sg;
    float wn = w * (1.f/sqrtf(fmaxf(nw, 1e-35f)));
    __syncthreads();
    su[r] = wn;
    __syncthreads();
  }
}

// ---------------- the scan: one WG per batch, all 200 steps on-chip ----------------
// EXACT round-9 verified structure (scan 7.12ms, total 8.72ms best).
// Serial D(X1) then F(h_raw) phases; J>=4 convergence-gated exit; weights from
// global/L1 (LDS staging measured slower, r6); no state held across barriers
// (VGPR cliff, r2/r5/r8); no phase merging (measured slower, r7/r10/r11).
__global__ __launch_bounds__(512, 1) void k_scan(
    const float* __restrict__ x, const float* __restrict__ b_hh,
    const float* __restrict__ bv,
    const float* __restrict__ whhT, const float* __restrict__ wzv,
    const float* __restrict__ wuv,
    const float* __restrict__ wp, const float* __restrict__ wr0,
    const float* __restrict__ sigma, float* __restrict__ outAL){
  __shared__ __align__(16) float L[19056];
  float* Rh  = L;            // [64][60] h (persistent across steps)
  float* R4  = L + 3840;     // [64][60] hg -> eigen pong
  float* R3  = L + 7680;     // [64][60] ZT -> eigen ping
  float* R2  = L + 11520;    // [53][64] val (preserved till h_raw)
  float* R1  = L + 14912;    // [56][60] S (preserved all step)
  float* Lp  = L + 18272;    // 192
  float* Lr0 = L + 18464;    // 192
  float* Lbh = L + 18656;    // 192
  float* Lbv = L + 18848;    // 64
  float* Lrq = L + 18912;    // 56
  float* Lrk = L + 18968;    // 56
  float* Lsc = L + 19024;    // 32: [2j]=ssq_j, [2j+1]=tr_j
  int tid = threadIdx.x;
  int b = blockIdx.x;

  for (int i = tid; i < 192; i += 512){ Lp[i] = wp[i]; Lr0[i] = wr0[i]; Lbh[i] = b_hh[i]; }
  for (int i = tid; i < 64; i += 512) Lbv[i] = bv[i];
  for (int i = tid; i < 18272; i += 512) L[i] = 0.f;  // zero Rh..R1 (h0=0, pads)
  __syncthreads();

  int ct4 = tid >> 4, jt4 = tid & 15;   // 224-thread tilings (GH / h_raw)
  int c0g = ct4*4, j0g = jt4*4;
  int it14 = tid/14, jt14 = tid%14;     // 196-thread scores tiling
  int i0s = it14*4, j0s = jt14*4;
  int ctq = tid >> 5, gtq = tid & 31;   // 448-thread QKV tiling
  int c0q = ctq*4, g0q = gtq*4;
  int erg = tid/14, ecg = tid%14;       // 378-thread eigen tiling (2x4)
  int er0 = erg*2, ec0 = ecg*4;

  const float c0v = wuv[128];

  for (int t = 0; t < T_; t++){
    // ---- A: GH + gates fused: gh = h @ w_hh^T (+b_hh); hg -> R4 (224 thr) ----
    if (tid < 32) Lsc[tid] = 0.f;
    if (tid < 224){
      float gacc[3][4][4];
      #pragma unroll
      for (int g = 0; g < 3; g++)
        #pragma unroll
        for (int ji = 0; ji < 4; ji++){
          float bb = Lbh[g*64 + j0g + ji];
          #pragma unroll
          for (int ci = 0; ci < 4; ci++) gacc[g][ji][ci] = bb;
        }
      for (int kk = 0; kk < 64; kk++){
        F4 hv = *(F4*)&Rh[kk*TS + c0g];
        F4 w0 = *(const F4*)&whhT[kk*192 + j0g];
        F4 w1 = *(const F4*)&whhT[kk*192 + 64 + j0g];
        F4 w2 = *(const F4*)&whhT[kk*192 + 128 + j0g];
        #pragma unroll
        for (int ji = 0; ji < 4; ji++)
          #pragma unroll
          for (int ci = 0; ci < 4; ci++){
            gacc[0][ji][ci] += hv.v[ci]*w0.v[ji];
            gacc[1][ji][ci] += hv.v[ci]*w1.v[ji];
            gacc[2][ji][ci] += hv.v[ci]*w2.v[ji];
          }
      }
      float xv[4];
      #pragma unroll
      for (int ci = 0; ci < 4; ci++){
        int c = c0g + ci;
        xv[ci] = (c < C_) ? x[(i64)(b*T_ + t)*C_ + c] : 0.f;
      }
      F4 p0 = *(F4*)&Lp[j0g], p1 = *(F4*)&Lp[64+j0g], p2 = *(F4*)&Lp[128+j0g];
      F4 q0 = *(F4*)&Lr0[j0g], q1 = *(F4*)&Lr0[64+j0g], q2 = *(F4*)&Lr0[128+j0g];
      #pragma unroll
      for (int ji = 0; ji < 4; ji++){
        F4 hold = *(F4*)&Rh[(j0g+ji)*TS + c0g];
        F4 o;
        #pragma unroll
        for (int ci = 0; ci < 4; ci++){
          float rr = sigm(xv[ci]*p0.v[ji] + q0.v[ji] + gacc[0][ji][ci]);
          float zz = sigm(xv[ci]*p1.v[ji] + q1.v[ji] + gacc[1][ji][ci]);
          float nn = tanhx(xv[ci]*p2.v[ji] + q2.v[ji] + rr*gacc[2][ji][ci]);
          float hg = (1.f - zz)*nn + zz*hold.v[ci];
          o.v[ci] = (c0g + ci < C_) ? hg : 0.f;
        }
        *(F4*)&R4[(j0g+ji)*TS + c0g] = o;
      }
    }
    __syncthreads();
    // ---- B: projections: ZT = (hg G)^T -> R3, val -> R2 (448); rank-1 vecs ----
    if (tid < 448){
      float acc[4][4];
      #pragma unroll
      for (int gi = 0; gi < 4; gi++)
        #pragma unroll
        for (int ci = 0; ci < 4; ci++) acc[gi][ci] = 0.f;
      for (int kk = 0; kk < 64; kk++){
        F4 a = *(F4*)&R4[kk*TS + c0q];
        F4 w = *(const F4*)&wzv[kk*128 + g0q];
        #pragma unroll
        for (int gi = 0; gi < 4; gi++)
          #pragma unroll
          for (int ci = 0; ci < 4; ci++) acc[gi][ci] += a.v[ci]*w.v[gi];
      }
      if (g0q < 64){
        #pragma unroll
        for (int gi = 0; gi < 4; gi++){
          F4 o;
          #pragma unroll
          for (int ci = 0; ci < 4; ci++) o.v[ci] = acc[gi][ci];
          *(F4*)&R3[(g0q+gi)*TS + c0q] = o;
        }
      } else {
        float invs = 1.f/sigma[t];
        int a0i = g0q - 64;
        #pragma unroll
        for (int ci = 0; ci < 4; ci++){
          int c = c0q + ci;
          if (c < C_){
            F4 o;
            #pragma unroll
            for (int gi = 0; gi < 4; gi++) o.v[gi] = acc[gi][ci]*invs + Lbv[a0i+gi];
            *(F4*)&R2[c*64 + a0i] = o;
          }
        }
      }
    } else if (tid < 504){
      int u = tid - 448;
      float rq = 0.f, rk = 0.f;
      if (u < C_){
        for (int h = 0; h < 64; h++){
          float hv = R4[h*TS + u];
          rq += hv*wuv[h];
          rk += hv*wuv[64+h];
        }
      }
      if (u < 56){ Lrq[u] = rq; Lrk[u] = rk; }
    }
    __syncthreads();
    // ---- C: scores S = ZT^T.hgT + rank1 -> R1 (196 thr, 4x4); stats ----
    {
      float sacc[4][4];
      float ssq = 0.f, trc = 0.f;
      if (tid < 196){
        #pragma unroll
        for (int ii = 0; ii < 4; ii++)
          #pragma unroll
          for (int jj = 0; jj < 4; jj++){
            int i = i0s + ii, j = j0s + jj;
            sacc[ii][jj] = (i < C_ && j < C_) ? (Lrq[i] + Lrk[j] + c0v) : 0.f;
          }
        for (int aq = 0; aq < 16; aq++){
          int a4 = aq*4;
          F4 qa0 = *(F4*)&R3[(a4+0)*TS + i0s];
          F4 qa1 = *(F4*)&R3[(a4+1)*TS + i0s];
          F4 qa2 = *(F4*)&R3[(a4+2)*TS + i0s];
          F4 qa3 = *(F4*)&R3[(a4+3)*TS + i0s];
          F4 kb0 = *(F4*)&R4[(a4+0)*TS + j0s];
          F4 kb1 = *(F4*)&R4[(a4+1)*TS + j0s];
          F4 kb2 = *(F4*)&R4[(a4+2)*TS + j0s];
          F4 kb3 = *(F4*)&R4[(a4+3)*TS + j0s];
          #pragma unroll
          for (int ii = 0; ii < 4; ii++)
            #pragma unroll
            for (int jj = 0; jj < 4; jj++)
              sacc[ii][jj] += qa0.v[ii]*kb0.v[jj] + qa1.v[ii]*kb1.v[jj]
                            + qa2.v[ii]*kb2.v[jj] + qa3.v[ii]*kb3.v[jj];
        }
        #pragma unroll
        for (int ii = 0; ii < 4; ii++){
          int i = i0s + ii;
          if (i < C_){
            F4 o;
            #pragma unroll
            for (int jj = 0; jj < 4; jj++){
              o.v[jj] = sacc[ii][jj];
              ssq += sacc[ii][jj]*sacc[ii][jj];
            }
            *(F4*)&R1[i*TS + j0s] = o;
            if (j0s <= i && i < j0s + 4) trc += sacc[ii][i - j0s];
          }
        }
      }
      ssq = wredsum(ssq); trc = wredsum(trc);
      if ((tid & 63) == 0){
        if (ssq != 0.f) atomicAdd(&Lsc[0], ssq);
        if (trc != 0.f) atomicAdd(&Lsc[1], trc);
      }
    }
    __syncthreads();
    // ---- D: first squaring X1 = S@S/ssq0 -> R3 (378 thr, 2x4), fused stats ----
    {
      float inv0 = 1.f/fmaxf(Lsc[0], 1e-35f);
      float essq = 0.f, etrc = 0.f;
      if (tid < 378) eig_mm(R1, R3, er0, ec0, inv0, essq, etrc);
      essq = wredsum(essq); etrc = wredsum(etrc);
      if ((tid & 63) == 0){
        if (essq != 0.f) atomicAdd(&Lsc[2], essq);
        if (etrc != 0.f) atomicAdd(&Lsc[3], etrc);
      }
    }
    __syncthreads();
    // ---- E: eigen squaring chain, fused stats ----
    float Gacc = 0.f, prevest = 1e30f, est = 0.f;
    int cnt = 0;
    float pssq = fmaxf(Lsc[0], 1e-35f), ptr1 = Lsc[1];
    float* Xb = R3; float* Yb = R4;
    for (int j = 2; j <= 13; j++){
      float sj = fmaxf(Lsc[2*(j-1)], 1e-35f);
      float tj = Lsc[2*(j-1)+1];
      int J = j - 2;
      float t1n = ptr1/sqrtf(pssq);
      float t2n = tj;
      float disc = 2.f*t2n - t1n*t1n;
      float rq = (disc >= 0.f) ? 0.5f*(fabsf(t1n) + sqrtf(disc))
                               : sqrtf(fmaxf(0.5f*(t1n*t1n - t2n), 1e-30f));
      rq = fminf(fmaxf(rq, 0.02f), 1.5f);
      est = Gacc + ldexpf(0.5f*log2f(pssq) + log2f(rq), -J);
      if (fabsf(est - prevest) < 1e-4f) cnt++; else cnt = 0;
      prevest = est;
      Gacc += ldexpf(log2f(pssq), -(J+1));
      if ((J >= 4 && cnt >= 1) || j == 13) break;
      pssq = sj; ptr1 = tj;
      {
        float inv = 1.f/sj;
        float essq = 0.f, etrc = 0.f;
        if (tid < 378) eig_mm(Xb, Yb, er0, ec0, inv, essq, etrc);
        essq = wredsum(essq); etrc = wredsum(etrc);
        if ((tid & 63) == 0){
          if (essq != 0.f) atomicAdd(&Lsc[2*j], essq);
          if (etrc != 0.f) atomicAdd(&Lsc[2*j+1], etrc);
        }
      }
      { float* tp = Xb; Xb = Yb; Yb = tp; }
      __syncthreads();
    }
    float invm = exp2f(-est);
    // ---- F: h' = (S@val)*invm -> Rh (224) ; align = S*invm -> global (196) ----
    if (tid < 224){
      float hraw0[4] = {0.f,0.f,0.f,0.f};
      float hraw1[4] = {0.f,0.f,0.f,0.f};
      float hraw2[4] = {0.f,0.f,0.f,0.f};
      float hraw3[4] = {0.f,0.f,0.f,0.f};
      for (int kq = 0; kq < 13; kq++){
        int k4 = kq*4;
        F4 a0 = *(F4*)&R1[(c0g+0)*TS + k4];
        F4 a1 = *(F4*)&R1[(c0g+1)*TS + k4];
        F4 a2 = *(F4*)&R1[(c0g+2)*TS + k4];
        F4 a3 = *(F4*)&R1[(c0g+3)*TS + k4];
        F4 b0 = *(F4*)&R2[(k4+0)*64 + j0g];
        F4 b1 = *(F4*)&R2[(k4+1)*64 + j0g];
        F4 b2 = *(F4*)&R2[(k4+2)*64 + j0g];
        F4 b3 = *(F4*)&R2[(k4+3)*64 + j0g];
        #pragma unroll
        for (int jj = 0; jj < 4; jj++){
          hraw0[jj] += a0.v[0]*b0.v[jj] + a0.v[1]*b1.v[jj] + a0.v[2]*b2.v[jj] + a0.v[3]*b3.v[jj];
          hraw1[jj] += a1.v[0]*b0.v[jj] + a1.v[1]*b1.v[jj] + a1.v[2]*b2.v[jj] + a1.v[3]*b3.v[jj];
          hraw2[jj] += a2.v[0]*b0.v[jj] + a2.v[1]*b1.v[jj] + a2.v[2]*b2.v[jj] + a2.v[3]*b3.v[jj];
          hraw3[jj] += a3.v[0]*b0.v[jj] + a3.v[1]*b1.v[jj] + a3.v[2]*b2.v[jj] + a3.v[3]*b3.v[jj];
        }
      }
      {
        const int k = 52;
        float a0 = R1[(c0g+0)*TS + k], a1 = R1[(c0g+1)*TS + k];
        float a2 = R1[(c0g+2)*TS + k], a3 = R1[(c0g+3)*TS + k];
        F4 bb = *(F4*)&R2[k*64 + j0g];
        #pragma unroll
        for (int jj = 0; jj < 4; jj++){
          hraw0[jj] += a0*bb.v[jj];
          hraw1[jj] += a1*bb.v[jj];
          hraw2[jj] += a2*bb.v[jj];
          hraw3[jj] += a3*bb.v[jj];
        }
      }
      #pragma unroll
      for (int jj = 0; jj < 4; jj++){
        F4 o;
        o.v[0] = (c0g + 0 < C_) ? hraw0[jj]*invm : 0.f;
        o.v[1] = (c0g + 1 < C_) ? hraw1[jj]*invm : 0.f;
        o.v[2] = (c0g + 2 < C_) ? hraw2[jj]*invm : 0.f;
        o.v[3] = (c0g + 3 < C_) ? hraw3[jj]*invm : 0.f;
        *(F4*)&Rh[(j0g+jj)*TS + c0g] = o;
      }
    } else if (tid < 420){
      int u = tid - 224;
      int i0 = (u/14)*4, j0 = (u%14)*4;
      float* ALrow = outAL + (i64)(b*T_ + t)*C2_;
      #pragma unroll
      for (int ii = 0; ii < 4; ii++){
        int i = i0 + ii;
        if (i < C_){
          F4 s = *(F4*)&R1[i*TS + j0];
          #pragma unroll
          for (int jj = 0; jj < 4; jj++){
            int jc = j0 + jj;
            if (jc < C_) ALrow[i*C_ + jc] = s.v[jj]*invm;
          }
        }
      }
    }
    __syncthreads();
  }
}

// ---------------- amean: T-mean of (already scaled) align ----------------
__global__ void k_amean(const float* __restrict__ AL, float* __restrict__ amean){
  int b = blockIdx.x/11, ch = blockIdx.x%11;
  int c2 = ch*256 + threadIdx.x;
  if (c2 >= C2_) return;
  float acc = 0.f;
  for (int t = 0; t < T_; t++)
    acc += AL[(i64)(b*T_ + t)*C2_ + c2];
  amean[(i64)b*C2_ + c2] = acc*(1.f/(float)T_);
}

// ---------------- e = (align * mean) @ w_g1^T  (K-split x4, atomics, 256 thr) ------
__global__ __launch_bounds__(256) void k_gemm1(const float* __restrict__ AL,
                                               const float* __restrict__ amean,
                                               const float* __restrict__ w_g1,
                                               float* __restrict__ e){
  __shared__ __align__(16) float At[64][68];
  __shared__ __align__(16) float Bt[64][148];
  int mt = blockIdx.x >> 2, ks = blockIdx.x & 3;
  int tid = threadIdx.x;
  float acc[4][10];
  #pragma unroll
  for (int ri = 0; ri < 4; ri++)
    #pragma unroll
    for (int ci = 0; ci < 10; ci++) acc[ri][ci] = 0.f;
  int rg = tid/14, cg = tid%14;   // 224 compute threads: 16 row-groups x 14 col-groups
  int r0 = rg*4, cc0 = cg*10;
  for (int kb = 0; kb < 11; kb++){
    int k0 = (ks*11 + kb)*64;
    for (int idx = tid; idx < 4096; idx += 256){
      int r = idx >> 6, i = idx & 63;
      int kk = k0 + i;
      int row = mt*64 + r, bb = row/T_;
      float v = 0.f;
      if (kk < C2_) v = AL[(i64)row*C2_ + kk]*amean[(i64)bb*C2_ + kk];
      At[i][r] = v;
    }
    for (int idx = tid; idx < 9216; idx += 256){
      int c = idx >> 6, i = idx & 63;
      int kk = k0 + i;
      float v = 0.f;
      if (c < E1_ && kk < C2_) v = w_g1[(i64)c*C2_ + kk];
      Bt[i][c] = v;
    }
    __syncthreads();
    if (tid < 224){
      for (int i = 0; i < 64; i++){
        F4 a = *(F4*)&At[i][r0];
        float bv[10];
        #pragma unroll
        for (int u = 0; u < 5; u++){
          F2 b2 = *(F2*)&Bt[i][cc0 + u*2];
          bv[u*2] = b2.v[0]; bv[u*2+1] = b2.v[1];
        }
        #pragma unroll
        for (int ri = 0; ri < 4; ri++)
          #pragma unroll
          for (int ci = 0; ci < 10; ci++)
            acc[ri][ci] += a.v[ri]*bv[ci];
      }
    }
    __syncthreads();
  }
  if (tid < 224){
    #pragma unroll
    for (int ri = 0; ri < 4; ri++)
      #pragma unroll
      for (int ci = 0; ci < 10; ci++){
        int c = cc0 + ci;
        if (c < E1_) atomicAdd(&e[(i64)(mt*64 + r0 + ri)*E1_ + c], acc[ri][ci]);
      }
  }
}

// ---------------- BN stats -> coefA/coefB (b_g1 absorbed by BN) ----------------
__global__ void k_bnstats(const float* __restrict__ e, const float* __restrict__ bn_g,
                          const float* __restrict__ bn_b, float* cA, float* cB){
  __shared__ float s1a[256], s2a[256];
  int c = blockIdx.x, tid = threadIdx.x;
  float s1 = 0.f, s2 = 0.f;
  for (int row = tid; row < B_*T_; row += 256){
    float v = e[(i64)row*E1_ + c];
    s1 += v; s2 += v*v;
  }
  s1a[tid] = s1; s2a[tid] = s2; __syncthreads();
  for (int s = 128; s > 0; s >>= 1){
    if (tid < s){ s1a[tid] += s1a[tid+s]; s2a[tid] += s2a[tid+s]; }
    __syncthreads();
  }
  if (tid == 0){
    float n = (float)(B_*T_);
    float mu = s1a[0]/n;
    float var = s2a[0]/n - mu*mu;
    float a = bn_g[c]/sqrtf(var + 1e-5f);
    cA[c] = a; cB[c] = bn_b[c] - mu*a;
  }
}

// ---------------- a_pre = relu(BN(e)) @ w_g2^T -> relu(+b_g2) . w_g3 (fused, atomics) ---
__global__ __launch_bounds__(128) void k_gemm2(const float* __restrict__ e,
                                               const float* __restrict__ cA, const float* __restrict__ cB,
                                               const float* __restrict__ g2t,
                                               const float* __restrict__ b_g2, const float* __restrict__ w_g3,
                                               float* __restrict__ apre){
  __shared__ __align__(16) float At2[140][68];
  int mt = blockIdx.x/30, nc = blockIdx.x%30;
  int tid = threadIdx.x;
  int nbase = nc*48;
  for (int idx = tid; idx < 64*140; idx += 128){
    int r = idx/140, k = idx - r*140;
    float v = e[(i64)(mt*64 + r)*E1_ + k]*cA[k] + cB[k];
    At2[k][r] = fmaxf(v, 0.f);
  }
  __syncthreads();
  if (tid < 96){
    int rg = tid/6, ng = tid%6;
    int r0 = rg*4, n0 = nbase + ng*8;
    float acc[4][8];
    #pragma unroll
    for (int ri = 0; ri < 4; ri++)
      #pragma unroll
      for (int ni = 0; ni < 8; ni++) acc[ri][ni] = 0.f;
    for (int k = 0; k < E1_; k++){
      F4 a = *(F4*)&At2[k][r0];
      float bvv[8];
      if (n0 + 8 <= E2_){
        F4 b0 = *(const F4*)&g2t[(i64)k*E2_ + n0];
        F4 b1 = *(const F4*)&g2t[(i64)k*E2_ + n0 + 4];
        #pragma unroll
        for (int u = 0; u < 4; u++){ bvv[u] = b0.v[u]; bvv[u+4] = b1.v[u]; }
      } else {
        #pragma unroll
        for (int ni = 0; ni < 8; ni++){ int n = n0+ni; bvv[ni] = (n < E2_) ? g2t[(i64)k*E2_ + n] : 0.f; }
      }
      #pragma unroll
      for (int ri = 0; ri < 4; ri++)
        #pragma unroll
        for (int ni = 0; ni < 8; ni++) acc[ri][ni] += a.v[ri]*bvv[ni];
    }
    #pragma unroll
    for (int ri = 0; ri < 4; ri++){
      float s = 0.f;
      #pragma unroll
      for (int ni = 0; ni < 8; ni++){
        int n = n0 + ni;
        if (n < E2_){
          float a2 = acc[ri][ni] + b_g2[n];
          if (a2 > 0.f) s += a2*w_g3[n];
        }
      }
      atomicAdd(&apre[mt*64 + r0 + ri], s);
    }
  }
}

// ---------------- softmax over T (b_g3 absorbed) + logits init ----------------
__global__ void k_soft(const float* __restrict__ apre, const float* __restrict__ b_clf,
                       float* __restrict__ wa, float* __restrict__ out){
  __shared__ float sr[256];
  int b = blockIdx.x, tid = threadIdx.x;
  float v = (tid < T_) ? apre[b*T_ + tid] : -3.4e38f;
  sr[tid] = v; __syncthreads();
  for (int s = 128; s > 0; s >>= 1){ if (tid < s) sr[tid] = fmaxf(sr[tid], sr[tid+s]); __syncthreads(); }
  float mx = sr[0]; __syncthreads();
  float ev = (tid < T_) ? __expf(v - mx) : 0.f;
  sr[tid] = ev; __syncthreads();
  for (int s = 128; s > 0; s >>= 1){ if (tid < s) sr[tid] += sr[tid+s]; __syncthreads(); }
  float den = sr[0];
  if (tid < T_) wa[b*T_ + tid] = ev/den;
  if (b == 0 && tid < 2*B_) out[tid] = b_clf[tid & 1];
}

// ---------------- dnc = sum_t align*a ; logits += dnc @ w_clf^T ----------------
__global__ void k_dnc(const float* __restrict__ AL, const float* __restrict__ wa,
                      const float* __restrict__ w_clf, float* __restrict__ out){
  int b = blockIdx.x/11, ch = blockIdx.x%11;
  int c2 = ch*256 + threadIdx.x;
  float acc = 0.f;
  if (c2 < C2_){
    for (int t = 0; t < T_; t++)
      acc += AL[(i64)(b*T_ + t)*C2_ + c2]*wa[b*T_ + t];
    out[96 + (i64)b*C2_ + c2] = acc;
  }
  float p0 = (c2 < C2_) ? acc*w_clf[c2]        : 0.f;
  float p1 = (c2 < C2_) ? acc*w_clf[C2_ + c2]  : 0.f;
  p0 = wredsum(p0); p1 = wredsum(p1);
  if ((threadIdx.x & 63) == 0){
    atomicAdd(&out[b*2 + 0], p0);
    atomicAdd(&out[b*2 + 1], p1);
  }
}

extern "C" void kernel_launch(void* const* d_in, const int* in_sizes, int n_in,
                              void* d_out, int out_size, void* d_ws, size_t ws_size,
                              hipStream_t stream){
  const float* x     = (const float*)d_in[0];
  const float* emb_w = (const float*)d_in[1];
  const float* emb_b = (const float*)d_in[2];
  const float* w_ih  = (const float*)d_in[3];
  const float* w_hh  = (const float*)d_in[4];
  const float* b_ih  = (const float*)d_in[5];
  const float* b_hh  = (const float*)d_in[6];
  const float* wq    = (const float*)d_in[7];
  const float* bq    = (const float*)d_in[8];
  const float* wk    = (const float*)d_in[9];
  const float* bk    = (const float*)d_in[10];
  const float* wv_in = (const float*)d_in[11];
  const float* bv    = (const float*)d_in[12];
  const float* u0    = (const float*)d_in[13];
  const float* w_g1  = (const float*)d_in[14];
  const float* bn_g  = (const float*)d_in[16];
  const float* bn_b  = (const float*)d_in[17];
  const float* w_g2  = (const float*)d_in[18];
  const float* b_g2  = (const float*)d_in[19];
  const float* w_g3  = (const float*)d_in[20];
  const float* w_clf = (const float*)d_in[22];
  const float* b_clf = (const float*)d_in[23];
  float* out = (float*)d_out;
  float* W = (float*)d_ws;

  float* wsig   = W + OFF_SIGMA;
  float* whhT   = W + OFF_WHHT;
  float* wzv    = W + OFF_WZV;
  float* wuv    = W + OFF_WUV;
  float* wp     = W + OFF_P;
  float* wr0    = W + OFF_R0;
  float* wM     = W + OFF_MM;
  float* wM2    = W + OFF_M2;
  float* wM4    = W + OFF_M4;
  float* wM5    = W + OFF_M5;
  float* wamean = W + OFF_AMEAN;
  float* we     = W + OFF_E;
  float* wcA    = W + OFF_CA;
  float* wcB    = W + OFF_CB;
  float* wapre  = W + OFF_APRE;
  float* wa     = W + OFF_A;
  float* wg2t   = W + OFF_G2T;

  float* outAL = out + 96 + (i64)B_*C2_;  // align region

  hipMemsetAsync(we, 0, (size_t)(B_*T_)*E1_*sizeof(float), stream);
  hipMemsetAsync(wapre, 0, (size_t)(B_*T_)*sizeof(float), stream);

  k_prep1<<<96, 256, 0, stream>>>(w_hh, wq, wk, wv_in, w_ih, emb_w, emb_b, b_ih, bq, bk,
                                  w_g2, whhT, wzv, wuv, wg2t, wp, wr0);
  k_prep2<<<1, 64, 0, stream>>>(wv_in, u0, wM, wM2, wM4, wM5, wsig);
  k_scan<<<B_, 512, 0, stream>>>(x, b_hh, bv, whhT, wzv, wuv, wp, wr0, wsig, outAL);
  k_amean<<<B_*11, 256, 0, stream>>>(outAL, wamean);
  k_gemm1<<<600, 256, 0, stream>>>(outAL, wamean, w_g1, we);
  k_bnstats<<<E1_, 256, 0, stream>>>(we, bn_g, bn_b, wcA, wcB);
  k_gemm2<<<150*30, 128, 0, stream>>>(we, wcA, wcB, wg2t, b_g2, w_g3, wapre);
  k_soft<<<B_, 256, 0, stream>>>(wapre, b_clf, wa, out);
  k_dnc<<<B_*11, 256, 0, stream>>>(outAL, wa, w_clf, out);
}